// Round 1
// baseline (529.234 us; speedup 1.0000x reference)
//
#include <hip/hip_runtime.h>

#define NVOX1 524288   // 2*64^3
#define NVOX2 65536    // 2*32^3
#define NVOX4 8192     // 2*16^3

// float offsets into ws (stats area, zeroed each launch)
#define ST_CNT1 0
#define ST_CNT2 1
#define ST_CNT4 2
#define ST_SUM1 16
#define ST_SQ1  24
#define ST_SUM2 32
#define ST_SQ2  48
#define ST_SUM3 64
#define ST_SQ3  96
#define ST_SUM3T 128
#define ST_SQ3T  144
#define ST_SUM2T 160
#define ST_SQ2T  176
#define FLAG_OFF 200   // 2 ints live at float slots 200,201
#define ST_ZERO 256    // number of floats memset to 0 each launch

// buffer offsets (in floats)
#define OFF_M1C 512
#define OFF_M2  (OFF_M1C + NVOX1)
#define OFF_M4  (OFF_M2 + NVOX2)
#define OFF_H1  (OFF_M4 + NVOX4)
#define OFF_S2  (OFF_H1 + NVOX1 * 8)
#define OFF_H3  (OFF_S2 + NVOX2 * 16)
#define OFF_T3  (OFF_H3 + NVOX4 * 32)

// ---------- mask format detection & canonicalization ----------
__global__ __launch_bounds__(256) void k_detect(const unsigned int* __restrict__ m,
                                                int* __restrict__ flags) {
  int tid = blockIdx.x * 256 + threadIdx.x;
  int hasf = 0, hasb = 0;
  for (int i = tid; i < NVOX1; i += 256 * 256) {
    unsigned int v = m[i];
    if (v == 0x3F800000u) hasf = 1;
    else if (v > 1u) hasb = 1;
  }
  hasf = __syncthreads_or(hasf);
  hasb = __syncthreads_or(hasb);
  if (threadIdx.x == 0) {
    if (hasf) atomicOr(&flags[0], 1);
    if (hasb) atomicOr(&flags[1], 1);
  }
}

__global__ __launch_bounds__(256) void k_canon(const void* __restrict__ mraw,
                                               int* __restrict__ m1c,
                                               const int* __restrict__ flags) {
  int idx = blockIdx.x * 256 + threadIdx.x;
  if (idx >= NVOX1) return;
  int isf = flags[0], isb = flags[1];
  int v;
  if (isf)      v = (((const float*)mraw)[idx] != 0.f);
  else if (isb) v = (((const unsigned char*)mraw)[idx] != 0);
  else          v = (((const int*)mraw)[idx] != 0);
  m1c[idx] = v;
}

// ---------- mask downsampling + active counts ----------
__global__ __launch_bounds__(256) void k_down1(const int* __restrict__ m1,
                                               int* __restrict__ m2,
                                               float* __restrict__ stats) {
  __shared__ float s_cnt;
  if (threadIdx.x == 0) s_cnt = 0.f;
  __syncthreads();
  int idx = blockIdx.x * 256 + threadIdx.x;  // 2*32^3
  int x = idx & 31, y = (idx >> 5) & 31, z = (idx >> 10) & 31, b = idx >> 15;
  int cnt = 0, any = 0;
#pragma unroll
  for (int dz = 0; dz < 2; dz++)
#pragma unroll
    for (int dy = 0; dy < 2; dy++)
#pragma unroll
      for (int dx = 0; dx < 2; dx++) {
        int v = m1[((b * 64 + 2 * z + dz) * 64 + 2 * y + dy) * 64 + 2 * x + dx];
        cnt += (v != 0);
        any |= v;
      }
  m2[idx] = any ? 1 : 0;
  if (cnt) atomicAdd(&s_cnt, (float)cnt);
  __syncthreads();
  if (threadIdx.x == 0 && s_cnt != 0.f) atomicAdd(&stats[ST_CNT1], s_cnt);
}

__global__ __launch_bounds__(256) void k_down2(const int* __restrict__ m2,
                                               int* __restrict__ m4,
                                               float* __restrict__ stats) {
  __shared__ float s_c2, s_c4;
  if (threadIdx.x == 0) { s_c2 = 0.f; s_c4 = 0.f; }
  __syncthreads();
  int idx = blockIdx.x * 256 + threadIdx.x;  // 2*16^3
  int x = idx & 15, y = (idx >> 4) & 15, z = (idx >> 8) & 15, b = idx >> 12;
  int cnt = 0, any = 0;
#pragma unroll
  for (int dz = 0; dz < 2; dz++)
#pragma unroll
    for (int dy = 0; dy < 2; dy++)
#pragma unroll
      for (int dx = 0; dx < 2; dx++) {
        int v = m2[((b * 32 + 2 * z + dz) * 32 + 2 * y + dy) * 32 + 2 * x + dx];
        cnt += (v != 0);
        any |= v;
      }
  m4[idx] = any ? 1 : 0;
  if (cnt) atomicAdd(&s_c2, (float)cnt);
  if (any) atomicAdd(&s_c4, 1.f);
  __syncthreads();
  if (threadIdx.x == 0) {
    if (s_c2 != 0.f) atomicAdd(&stats[ST_CNT2], s_c2);
    if (s_c4 != 0.f) atomicAdd(&stats[ST_CNT4], s_c4);
  }
}

// ---------- conv1: 64^3, 4->8, stride 1, + BN1 stats ----------
__global__ __launch_bounds__(256) void k_conv1(const float* __restrict__ x,
                                               const int* __restrict__ m1,
                                               const float* __restrict__ w,
                                               float* __restrict__ h1,
                                               float* __restrict__ stats) {
  __shared__ float s_w[864];
  __shared__ float s_st[16];
  for (int i = threadIdx.x; i < 864; i += 256) s_w[i] = w[i];
  if (threadIdx.x < 16) s_st[threadIdx.x] = 0.f;
  __syncthreads();
  int idx = blockIdx.x * 256 + threadIdx.x;
  int vx = idx & 63, vy = (idx >> 6) & 63, vz = (idx >> 12) & 63, vb = idx >> 18;
  float* hp = h1 + (size_t)idx * 8;
  if (m1[idx]) {
    float acc[8];
#pragma unroll
    for (int c = 0; c < 8; c++) acc[c] = 0.f;
    for (int kd = 0; kd < 3; kd++) {
      int d = vz + kd - 1; if (d < 0 || d >= 64) continue;
      for (int kh = 0; kh < 3; kh++) {
        int h = vy + kh - 1; if (h < 0 || h >= 64) continue;
        for (int kw = 0; kw < 3; kw++) {
          int ww = vx + kw - 1; if (ww < 0 || ww >= 64) continue;
          int ni = ((vb * 64 + d) * 64 + h) * 64 + ww;
          if (!m1[ni]) continue;
          const float* ip = x + (size_t)ni * 4;
          const float* wp = s_w + ((kd * 3 + kh) * 3 + kw) * 32;
#pragma unroll
          for (int ci = 0; ci < 4; ci++) {
            float v = ip[ci];
#pragma unroll
            for (int co = 0; co < 8; co++) acc[co] += v * wp[ci * 8 + co];
          }
        }
      }
    }
#pragma unroll
    for (int c = 0; c < 8; c++) {
      hp[c] = acc[c];
      atomicAdd(&s_st[c], acc[c]);
      atomicAdd(&s_st[8 + c], acc[c] * acc[c]);
    }
  } else {
#pragma unroll
    for (int c = 0; c < 8; c++) hp[c] = 0.f;
  }
  __syncthreads();
  if (threadIdx.x < 16 && s_st[threadIdx.x] != 0.f)
    atomicAdd(&stats[ST_SUM1 + threadIdx.x], s_st[threadIdx.x]);
}

// ---------- generic BN apply (scale/bias recomputed per block) ----------
__global__ __launch_bounds__(256) void k_apply(float* __restrict__ buf,
                                               const int* __restrict__ mask,
                                               const float* __restrict__ g,
                                               const float* __restrict__ be,
                                               const float* __restrict__ stats,
                                               int C, int sumOff, int sqOff, int cntOff,
                                               int relu, int nvox) {
  __shared__ float s_sc[32], s_bi[32];
  int t = threadIdx.x;
  if (t < C) {
    float cnt = fmaxf(stats[cntOff], 1.f);
    float mean = stats[sumOff + t] / cnt;
    float var = fmaxf(stats[sqOff + t] / cnt - mean * mean, 0.f);
    float sc = g[t] * rsqrtf(var + 1e-5f);
    s_sc[t] = sc;
    s_bi[t] = be[t] - mean * sc;
  }
  __syncthreads();
  int idx = blockIdx.x * 256 + t;
  if (idx >= nvox || !mask[idx]) return;
  float* p = buf + (size_t)idx * C;
  for (int c = 0; c < C; c++) {
    float v = p[c] * s_sc[c] + s_bi[c];
    if (relu) v = fmaxf(v, 0.f);
    p[c] = v;
  }
}

// ---------- conv2: 64^3 -> 32^3, 8->16, stride 2, reads relu(s1) ----------
__global__ __launch_bounds__(256) void k_conv2(const float* __restrict__ s1,
                                               const int* __restrict__ m1,
                                               const int* __restrict__ m2,
                                               const float* __restrict__ w,
                                               float* __restrict__ h2,
                                               float* __restrict__ stats) {
  __shared__ float s_w[3456];
  __shared__ float s_st[32];
  for (int i = threadIdx.x; i < 3456; i += 256) s_w[i] = w[i];
  if (threadIdx.x < 32) s_st[threadIdx.x] = 0.f;
  __syncthreads();
  int idx = blockIdx.x * 256 + threadIdx.x;
  int vx = idx & 31, vy = (idx >> 5) & 31, vz = (idx >> 10) & 31, vb = idx >> 15;
  float* hp = h2 + (size_t)idx * 16;
  if (m2[idx]) {
    float acc[16];
#pragma unroll
    for (int c = 0; c < 16; c++) acc[c] = 0.f;
    for (int kd = 0; kd < 3; kd++) {
      int d = 2 * vz + kd - 1; if (d < 0 || d >= 64) continue;
      for (int kh = 0; kh < 3; kh++) {
        int h = 2 * vy + kh - 1; if (h < 0 || h >= 64) continue;
        for (int kw = 0; kw < 3; kw++) {
          int ww = 2 * vx + kw - 1; if (ww < 0 || ww >= 64) continue;
          int ni = ((vb * 64 + d) * 64 + h) * 64 + ww;
          if (!m1[ni]) continue;
          const float* ip = s1 + (size_t)ni * 8;
          const float* wp = s_w + ((kd * 3 + kh) * 3 + kw) * 128;
#pragma unroll
          for (int ci = 0; ci < 8; ci++) {
            float v = fmaxf(ip[ci], 0.f);
#pragma unroll
            for (int co = 0; co < 16; co++) acc[co] += v * wp[ci * 16 + co];
          }
        }
      }
    }
#pragma unroll
    for (int c = 0; c < 16; c++) {
      hp[c] = acc[c];
      atomicAdd(&s_st[c], acc[c]);
      atomicAdd(&s_st[16 + c], acc[c] * acc[c]);
    }
  } else {
#pragma unroll
    for (int c = 0; c < 16; c++) hp[c] = 0.f;
  }
  __syncthreads();
  if (threadIdx.x < 32 && s_st[threadIdx.x] != 0.f)
    atomicAdd(&stats[ST_SUM2 + threadIdx.x], s_st[threadIdx.x]);
}

// ---------- conv3: 32^3 -> 16^3, 16->32, stride 2, reads relu(s2) ----------
__global__ __launch_bounds__(256) void k_conv3(const float* __restrict__ s2v,
                                               const int* __restrict__ m2,
                                               const int* __restrict__ m4,
                                               const float* __restrict__ w,
                                               float* __restrict__ h3,
                                               float* __restrict__ stats) {
  __shared__ float s_w[13824];
  __shared__ float s_st[64];
  for (int i = threadIdx.x; i < 13824; i += 256) s_w[i] = w[i];
  if (threadIdx.x < 64) s_st[threadIdx.x] = 0.f;
  __syncthreads();
  int idx = blockIdx.x * 256 + threadIdx.x;
  int vx = idx & 15, vy = (idx >> 4) & 15, vz = (idx >> 8) & 15, vb = idx >> 12;
  float* hp = h3 + (size_t)idx * 32;
  if (m4[idx]) {
    float acc[32];
#pragma unroll
    for (int c = 0; c < 32; c++) acc[c] = 0.f;
    for (int kd = 0; kd < 3; kd++) {
      int d = 2 * vz + kd - 1; if (d < 0 || d >= 32) continue;
      for (int kh = 0; kh < 3; kh++) {
        int h = 2 * vy + kh - 1; if (h < 0 || h >= 32) continue;
        for (int kw = 0; kw < 3; kw++) {
          int ww = 2 * vx + kw - 1; if (ww < 0 || ww >= 32) continue;
          int ni = ((vb * 32 + d) * 32 + h) * 32 + ww;
          if (!m2[ni]) continue;
          const float* ip = s2v + (size_t)ni * 16;
          const float* wp = s_w + ((kd * 3 + kh) * 3 + kw) * 512;
#pragma unroll
          for (int ci = 0; ci < 16; ci++) {
            float v = fmaxf(ip[ci], 0.f);
#pragma unroll
            for (int co = 0; co < 32; co++) acc[co] += v * wp[ci * 32 + co];
          }
        }
      }
    }
#pragma unroll
    for (int c = 0; c < 32; c++) {
      hp[c] = acc[c];
      atomicAdd(&s_st[c], acc[c]);
      atomicAdd(&s_st[32 + c], acc[c] * acc[c]);
    }
  } else {
#pragma unroll
    for (int c = 0; c < 32; c++) hp[c] = 0.f;
  }
  __syncthreads();
  if (threadIdx.x < 64 && s_st[threadIdx.x] != 0.f)
    atomicAdd(&stats[ST_SUM3 + threadIdx.x], s_st[threadIdx.x]);
}

// ---------- transpose-conv tap enumeration (stride-2, kernel-3, centered) ----------
__device__ __forceinline__ int taps1d(int p, int gin, int* c, int* k) {
  if ((p & 1) == 0) { c[0] = p >> 1; k[0] = 1; return 1; }
  int n = 0;
  c[n] = (p - 1) >> 1; k[n] = 0; n++;
  int c2 = (p + 1) >> 1;
  if (c2 < gin) { c[n] = c2; k[n] = 2; n++; }
  return n;
}

// ---------- convt3: 16^3 -> 32^3, 32->16 ----------
__global__ __launch_bounds__(256) void k_convt3(const float* __restrict__ o4,
                                                const int* __restrict__ m2,
                                                const float* __restrict__ w,
                                                float* __restrict__ t3,
                                                float* __restrict__ stats) {
  __shared__ float s_w[13824];
  __shared__ float s_st[32];
  for (int i = threadIdx.x; i < 13824; i += 256) s_w[i] = w[i];
  if (threadIdx.x < 32) s_st[threadIdx.x] = 0.f;
  __syncthreads();
  int idx = blockIdx.x * 256 + threadIdx.x;
  int px = idx & 31, py = (idx >> 5) & 31, pz = (idx >> 10) & 31, vb = idx >> 15;
  float* op = t3 + (size_t)idx * 16;
  if (m2[idx]) {
    int cz[2], kz[2], cy[2], ky[2], cx[2], kx[2];
    int nz = taps1d(pz, 16, cz, kz);
    int ny = taps1d(py, 16, cy, ky);
    int nx = taps1d(px, 16, cx, kx);
    float acc[16];
#pragma unroll
    for (int c = 0; c < 16; c++) acc[c] = 0.f;
    for (int iz = 0; iz < nz; iz++)
      for (int iy = 0; iy < ny; iy++)
        for (int ix = 0; ix < nx; ix++) {
          int ni = ((vb * 16 + cz[iz]) * 16 + cy[iy]) * 16 + cx[ix];
          const float* ip = o4 + (size_t)ni * 32;
          const float* wp = s_w + ((kz[iz] * 3 + ky[iy]) * 3 + kx[ix]) * 512;
#pragma unroll
          for (int ci = 0; ci < 32; ci++) {
            float v = ip[ci];
#pragma unroll
            for (int co = 0; co < 16; co++) acc[co] += v * wp[ci * 16 + co];
          }
        }
#pragma unroll
    for (int c = 0; c < 16; c++) {
      op[c] = acc[c];
      atomicAdd(&s_st[c], acc[c]);
      atomicAdd(&s_st[16 + c], acc[c] * acc[c]);
    }
  } else {
#pragma unroll
    for (int c = 0; c < 16; c++) op[c] = 0.f;
  }
  __syncthreads();
  if (threadIdx.x < 32 && s_st[threadIdx.x] != 0.f)
    atomicAdd(&stats[ST_SUM3T + threadIdx.x], s_st[threadIdx.x]);
}

// ---------- convt2: 32^3 -> 64^3, concat(t3,s2)=32 -> 16; raw -> d_out ----------
__global__ __launch_bounds__(256) void k_convt2(const float* __restrict__ t3,
                                                const float* __restrict__ s2v,
                                                const int* __restrict__ m1,
                                                const int* __restrict__ m2,
                                                const float* __restrict__ w,
                                                float* __restrict__ outraw,
                                                float* __restrict__ stats) {
  __shared__ float s_w[13824];
  __shared__ float s_st[32];
  for (int i = threadIdx.x; i < 13824; i += 256) s_w[i] = w[i];
  if (threadIdx.x < 32) s_st[threadIdx.x] = 0.f;
  __syncthreads();
  int idx = blockIdx.x * 256 + threadIdx.x;
  int px = idx & 63, py = (idx >> 6) & 63, pz = (idx >> 12) & 63, vb = idx >> 18;
  if (m1[idx]) {
    int cz[2], kz[2], cy[2], ky[2], cx[2], kx[2];
    int nz = taps1d(pz, 32, cz, kz);
    int ny = taps1d(py, 32, cy, ky);
    int nx = taps1d(px, 32, cx, kx);
    float acc[16];
#pragma unroll
    for (int c = 0; c < 16; c++) acc[c] = 0.f;
    for (int iz = 0; iz < nz; iz++)
      for (int iy = 0; iy < ny; iy++)
        for (int ix = 0; ix < nx; ix++) {
          int ni = ((vb * 32 + cz[iz]) * 32 + cy[iy]) * 32 + cx[ix];
          if (!m2[ni]) continue;
          const float* tp = t3 + (size_t)ni * 16;
          const float* sp = s2v + (size_t)ni * 16;
          const float* wp = s_w + ((kz[iz] * 3 + ky[iy]) * 3 + kx[ix]) * 512;
#pragma unroll
          for (int ci = 0; ci < 16; ci++) {
            float v = tp[ci];
#pragma unroll
            for (int co = 0; co < 16; co++) acc[co] += v * wp[ci * 16 + co];
          }
#pragma unroll
          for (int ci = 0; ci < 16; ci++) {
            float v = sp[ci];
#pragma unroll
            for (int co = 0; co < 16; co++) acc[co] += v * wp[(16 + ci) * 16 + co];
          }
        }
    float* op = outraw + (size_t)idx * 16;
#pragma unroll
    for (int c = 0; c < 16; c++) {
      op[c] = acc[c];
      atomicAdd(&s_st[c], acc[c]);
      atomicAdd(&s_st[16 + c], acc[c] * acc[c]);
    }
  }
  __syncthreads();
  if (threadIdx.x < 32 && s_st[threadIdx.x] != 0.f)
    atomicAdd(&stats[ST_SUM2T + threadIdx.x], s_st[threadIdx.x]);
}

// ---------- final: BN2t + relu + concat s1 + 1x1 conv + mask ----------
__global__ __launch_bounds__(256) void k_final(float* __restrict__ out,
                                               const float* __restrict__ s1,
                                               const int* __restrict__ m1,
                                               const float* __restrict__ g,
                                               const float* __restrict__ be,
                                               const float* __restrict__ w1x1,
                                               const float* __restrict__ stats) {
  __shared__ float s_sc[16], s_bi[16], s_w[384];
  int t = threadIdx.x;
  for (int i = t; i < 384; i += 256) s_w[i] = w1x1[i];
  if (t < 16) {
    float cnt = fmaxf(stats[ST_CNT1], 1.f);
    float mean = stats[ST_SUM2T + t] / cnt;
    float var = fmaxf(stats[ST_SQ2T + t] / cnt - mean * mean, 0.f);
    float sc = g[t] * rsqrtf(var + 1e-5f);
    s_sc[t] = sc;
    s_bi[t] = be[t] - mean * sc;
  }
  __syncthreads();
  int idx = blockIdx.x * 256 + t;
  float* op = out + (size_t)idx * 16;
  if (!m1[idx]) {
#pragma unroll
    for (int c = 0; c < 16; c++) op[c] = 0.f;
    return;
  }
  float t2[16];
#pragma unroll
  for (int c = 0; c < 16; c++) t2[c] = fmaxf(op[c] * s_sc[c] + s_bi[c], 0.f);
  float s1v[8];
#pragma unroll
  for (int c = 0; c < 8; c++) s1v[c] = s1[(size_t)idx * 8 + c];
  float o[16];
#pragma unroll
  for (int oc = 0; oc < 16; oc++) o[oc] = 0.f;
#pragma unroll
  for (int c = 0; c < 16; c++) {
    float v = t2[c];
#pragma unroll
    for (int oc = 0; oc < 16; oc++) o[oc] += v * s_w[c * 16 + oc];
  }
#pragma unroll
  for (int c = 0; c < 8; c++) {
    float v = s1v[c];
#pragma unroll
    for (int oc = 0; oc < 16; oc++) o[oc] += v * s_w[(16 + c) * 16 + oc];
  }
#pragma unroll
  for (int oc = 0; oc < 16; oc++) op[oc] = o[oc];
}

extern "C" void kernel_launch(void* const* d_in, const int* in_sizes, int n_in,
                              void* d_out, int out_size, void* d_ws, size_t ws_size,
                              hipStream_t stream) {
  const float* x    = (const float*)d_in[0];
  const void*  mraw = d_in[1];
  const float* w1   = (const float*)d_in[2];
  const float* g1   = (const float*)d_in[3];
  const float* b1   = (const float*)d_in[4];
  const float* w2   = (const float*)d_in[5];
  const float* g2   = (const float*)d_in[6];
  const float* b2   = (const float*)d_in[7];
  const float* w3   = (const float*)d_in[8];
  const float* g3   = (const float*)d_in[9];
  const float* b3   = (const float*)d_in[10];
  const float* w3t  = (const float*)d_in[11];
  const float* g3t  = (const float*)d_in[12];
  const float* b3t  = (const float*)d_in[13];
  const float* w2t  = (const float*)d_in[14];
  const float* g2t  = (const float*)d_in[15];
  const float* b2t  = (const float*)d_in[16];
  const float* w1x1 = (const float*)d_in[17];

  float* ws = (float*)d_ws;
  float* stats = ws;
  int* flags = (int*)(ws + FLAG_OFF);
  int* m1c = (int*)(ws + OFF_M1C);
  int* m2  = (int*)(ws + OFF_M2);
  int* m4  = (int*)(ws + OFF_M4);
  float* h1 = ws + OFF_H1;   // also s1 after apply
  float* s2 = ws + OFF_S2;
  float* h3 = ws + OFF_H3;   // also o4 after apply
  float* t3 = ws + OFF_T3;
  float* out = (float*)d_out;

  hipMemsetAsync(ws, 0, ST_ZERO * sizeof(float), stream);
  k_detect<<<256, 256, 0, stream>>>((const unsigned int*)mraw, flags);
  k_canon<<<NVOX1 / 256, 256, 0, stream>>>(mraw, m1c, flags);
  k_down1<<<NVOX2 / 256, 256, 0, stream>>>(m1c, m2, stats);
  k_down2<<<NVOX4 / 256, 256, 0, stream>>>(m2, m4, stats);
  k_conv1<<<NVOX1 / 256, 256, 0, stream>>>(x, m1c, w1, h1, stats);
  k_apply<<<NVOX1 / 256, 256, 0, stream>>>(h1, m1c, g1, b1, stats, 8, ST_SUM1, ST_SQ1, ST_CNT1, 0, NVOX1);
  k_conv2<<<NVOX2 / 256, 256, 0, stream>>>(h1, m1c, m2, w2, s2, stats);
  k_apply<<<NVOX2 / 256, 256, 0, stream>>>(s2, m2, g2, b2, stats, 16, ST_SUM2, ST_SQ2, ST_CNT2, 0, NVOX2);
  k_conv3<<<NVOX4 / 256, 256, 0, stream>>>(s2, m2, m4, w3, h3, stats);
  k_apply<<<NVOX4 / 256, 256, 0, stream>>>(h3, m4, g3, b3, stats, 32, ST_SUM3, ST_SQ3, ST_CNT4, 1, NVOX4);
  k_convt3<<<NVOX2 / 256, 256, 0, stream>>>(h3, m2, w3t, t3, stats);
  k_apply<<<NVOX2 / 256, 256, 0, stream>>>(t3, m2, g3t, b3t, stats, 16, ST_SUM3T, ST_SQ3T, ST_CNT2, 1, NVOX2);
  k_convt2<<<NVOX1 / 256, 256, 0, stream>>>(t3, s2, m1c, m2, w2t, out, stats);
  k_final<<<NVOX1 / 256, 256, 0, stream>>>(out, h1, m1c, g2t, b2t, w1x1, stats);
}

// Round 2
// 430.426 us; speedup vs baseline: 1.2296x; 1.2296x over previous
//
#include <hip/hip_runtime.h>

#define NVOX1 524288   // 2*64^3
#define NVOX2 65536    // 2*32^3
#define NVOX4 8192     // 2*16^3

// float offsets into ws (stats area, zeroed each launch)
#define ST_CNT1 0
#define ST_CNT2 1
#define ST_CNT4 2
#define ST_SUM1 16
#define ST_SQ1  24
#define ST_SUM2 32
#define ST_SQ2  48
#define ST_SUM3 64
#define ST_SQ3  96
#define ST_SUM3T 128
#define ST_SQ3T  144
#define ST_SUM2T 160
#define ST_SQ2T  176
#define FLAG_OFF 200
#define ST_ZERO 256

// buffer offsets (in floats)
#define OFF_M1C 512
#define OFF_M2  (OFF_M1C + NVOX1)
#define OFF_M4  (OFF_M2 + NVOX2)
#define OFF_H1  (OFF_M4 + NVOX4)
#define OFF_S2  (OFF_H1 + NVOX1 * 8)
#define OFF_H3  (OFF_S2 + NVOX2 * 16)
#define OFF_T3  (OFF_H3 + NVOX4 * 32)

#define EPSBN 1e-5f

// ---------- helpers ----------
template <int C>
__device__ __forceinline__ void wreduce(float& a, float& b) {
#pragma unroll
  for (int off = C; off < 64; off <<= 1) {
    a += __shfl_xor(a, off, 64);
    b += __shfl_xor(b, off, 64);
  }
}

__device__ __forceinline__ int taps1d(int p, int gin, int* c, int* k) {
  if ((p & 1) == 0) { c[0] = p >> 1; k[0] = 1; return 1; }
  int n = 0;
  c[n] = (p - 1) >> 1; k[n] = 0; n++;
  int c2 = (p + 1) >> 1;
  if (c2 < gin) { c[n] = c2; k[n] = 2; n++; }
  return n;
}

// ---------- mask format detection & canonicalization ----------
__global__ __launch_bounds__(256) void k_detect(const unsigned int* __restrict__ m,
                                                int* __restrict__ flags) {
  int tid = blockIdx.x * 256 + threadIdx.x;
  int hasf = 0, hasb = 0;
  for (int i = tid; i < NVOX1; i += 256 * 256) {
    unsigned int v = m[i];
    if (v == 0x3F800000u) hasf = 1;
    else if (v > 1u) hasb = 1;
  }
  hasf = __syncthreads_or(hasf);
  hasb = __syncthreads_or(hasb);
  if (threadIdx.x == 0) {
    if (hasf) atomicOr(&flags[0], 1);
    if (hasb) atomicOr(&flags[1], 1);
  }
}

__global__ __launch_bounds__(256) void k_canon(const void* __restrict__ mraw,
                                               int* __restrict__ m1c,
                                               const int* __restrict__ flags) {
  int idx = blockIdx.x * 256 + threadIdx.x;
  if (idx >= NVOX1) return;
  int isf = flags[0], isb = flags[1];
  int v;
  if (isf)      v = (((const float*)mraw)[idx] != 0.f);
  else if (isb) v = (((const unsigned char*)mraw)[idx] != 0);
  else          v = (((const int*)mraw)[idx] != 0);
  m1c[idx] = v;
}

// ---------- mask downsampling + active counts ----------
__global__ __launch_bounds__(256) void k_down1(const int* __restrict__ m1,
                                               int* __restrict__ m2,
                                               float* __restrict__ stats) {
  __shared__ float s_cnt;
  if (threadIdx.x == 0) s_cnt = 0.f;
  __syncthreads();
  int idx = blockIdx.x * 256 + threadIdx.x;
  int x = idx & 31, y = (idx >> 5) & 31, z = (idx >> 10) & 31, b = idx >> 15;
  int cnt = 0, any = 0;
#pragma unroll
  for (int dz = 0; dz < 2; dz++)
#pragma unroll
    for (int dy = 0; dy < 2; dy++)
#pragma unroll
      for (int dx = 0; dx < 2; dx++) {
        int v = m1[((b * 64 + 2 * z + dz) * 64 + 2 * y + dy) * 64 + 2 * x + dx];
        cnt += (v != 0);
        any |= v;
      }
  m2[idx] = any ? 1 : 0;
  if (cnt) atomicAdd(&s_cnt, (float)cnt);
  __syncthreads();
  if (threadIdx.x == 0 && s_cnt != 0.f) atomicAdd(&stats[ST_CNT1], s_cnt);
}

__global__ __launch_bounds__(256) void k_down2(const int* __restrict__ m2,
                                               int* __restrict__ m4,
                                               float* __restrict__ stats) {
  __shared__ float s_c2, s_c4;
  if (threadIdx.x == 0) { s_c2 = 0.f; s_c4 = 0.f; }
  __syncthreads();
  int idx = blockIdx.x * 256 + threadIdx.x;
  int x = idx & 15, y = (idx >> 4) & 15, z = (idx >> 8) & 15, b = idx >> 12;
  int cnt = 0, any = 0;
#pragma unroll
  for (int dz = 0; dz < 2; dz++)
#pragma unroll
    for (int dy = 0; dy < 2; dy++)
#pragma unroll
      for (int dx = 0; dx < 2; dx++) {
        int v = m2[((b * 32 + 2 * z + dz) * 32 + 2 * y + dy) * 32 + 2 * x + dx];
        cnt += (v != 0);
        any |= v;
      }
  m4[idx] = any ? 1 : 0;
  if (cnt) atomicAdd(&s_c2, (float)cnt);
  if (any) atomicAdd(&s_c4, 1.f);
  __syncthreads();
  if (threadIdx.x == 0) {
    if (s_c2 != 0.f) atomicAdd(&stats[ST_CNT2], s_c2);
    if (s_c4 != 0.f) atomicAdd(&stats[ST_CNT4], s_c4);
  }
}

// ---------- conv1: 64^3, 4->8 raw, thread=(voxel,co), grid 2048 x 8 iters ----------
__global__ __launch_bounds__(256) void k_conv1(const float* __restrict__ x,
                                               const int* __restrict__ m1,
                                               const float* __restrict__ w,
                                               float* __restrict__ h1,
                                               float* __restrict__ stats) {
  __shared__ float s_w[864];
  __shared__ float s_sum[8], s_sq[8];
  int t = threadIdx.x;
  { const float4* w4 = (const float4*)w; float4* sw4 = (float4*)s_w;
    for (int i = t; i < 216; i += 256) sw4[i] = w4[i]; }
  if (t < 8) { s_sum[t] = 0.f; s_sq[t] = 0.f; }
  __syncthreads();
  int co = t & 7, slot = t >> 3;  // 32 slots
  float sum = 0.f, sq = 0.f;
  for (int it = 0; it < 8; ++it) {
    int v = (it * 2048 + blockIdx.x) * 32 + slot;
    if (!m1[v]) continue;
    int vx = v & 63, vy = (v >> 6) & 63, vz = (v >> 12) & 63, vb = v >> 18;
    float acc = 0.f;
    for (int kd = 0; kd < 3; kd++) { int d = vz + kd - 1; if ((unsigned)d >= 64u) continue;
      for (int kh = 0; kh < 3; kh++) { int h = vy + kh - 1; if ((unsigned)h >= 64u) continue;
        for (int kw = 0; kw < 3; kw++) { int ww = vx + kw - 1; if ((unsigned)ww >= 64u) continue;
          int ni = ((vb * 64 + d) * 64 + h) * 64 + ww;
          if (!m1[ni]) continue;
          float4 ip = *(const float4*)(x + (size_t)ni * 4);
          const float* wp = s_w + ((kd * 3 + kh) * 3 + kw) * 32 + co;
          acc = fmaf(ip.x, wp[0], acc);
          acc = fmaf(ip.y, wp[8], acc);
          acc = fmaf(ip.z, wp[16], acc);
          acc = fmaf(ip.w, wp[24], acc);
        } } }
    h1[(size_t)v * 8 + co] = acc;
    sum += acc; sq += acc * acc;
  }
  wreduce<8>(sum, sq);
  if ((t & 63) < 8) { atomicAdd(&s_sum[co], sum); atomicAdd(&s_sq[co], sq); }
  __syncthreads();
  if (t < 8) {
    if (s_sum[t] != 0.f) atomicAdd(&stats[ST_SUM1 + t], s_sum[t]);
    if (s_sq[t]  != 0.f) atomicAdd(&stats[ST_SQ1 + t], s_sq[t]);
  }
}

// ---------- conv2: 64^3 -> 32^3, 8->16 raw; applies BN1+relu inline ----------
__global__ __launch_bounds__(256) void k_conv2(const float* __restrict__ h1,
                                               const int* __restrict__ m1,
                                               const int* __restrict__ m2,
                                               const float* __restrict__ w,
                                               const float* __restrict__ g1,
                                               const float* __restrict__ b1,
                                               float* __restrict__ s2,
                                               float* __restrict__ stats) {
  __shared__ float s_w[3456];
  __shared__ float s_sc[8], s_bi[8];
  __shared__ float s_sum[16], s_sq[16];
  int t = threadIdx.x;
  { const float4* w4 = (const float4*)w; float4* sw4 = (float4*)s_w;
    for (int i = t; i < 864; i += 256) sw4[i] = w4[i]; }
  if (t < 8) {
    float cnt = fmaxf(stats[ST_CNT1], 1.f);
    float mean = stats[ST_SUM1 + t] / cnt;
    float var = fmaxf(stats[ST_SQ1 + t] / cnt - mean * mean, 0.f);
    float sc = g1[t] * rsqrtf(var + EPSBN);
    s_sc[t] = sc; s_bi[t] = b1[t] - mean * sc;
  }
  if (t < 16) { s_sum[t] = 0.f; s_sq[t] = 0.f; }
  __syncthreads();
  int co = t & 15, slot = t >> 4;  // 16 slots
  float sum = 0.f, sq = 0.f;
  for (int it = 0; it < 2; ++it) {
    int v = (it * 2048 + blockIdx.x) * 16 + slot;
    if (m2[v]) {
      int vx = v & 31, vy = (v >> 5) & 31, vz = (v >> 10) & 31, vb = v >> 15;
      float acc = 0.f;
      for (int kd = 0; kd < 3; kd++) { int d = 2 * vz + kd - 1; if ((unsigned)d >= 64u) continue;
        for (int kh = 0; kh < 3; kh++) { int h = 2 * vy + kh - 1; if ((unsigned)h >= 64u) continue;
          for (int kw = 0; kw < 3; kw++) { int ww = 2 * vx + kw - 1; if ((unsigned)ww >= 64u) continue;
            int ni = ((vb * 64 + d) * 64 + h) * 64 + ww;
            if (!m1[ni]) continue;
            float4 i0 = *(const float4*)(h1 + (size_t)ni * 8);
            float4 i1 = *(const float4*)(h1 + (size_t)ni * 8 + 4);
            float r[8] = {i0.x, i0.y, i0.z, i0.w, i1.x, i1.y, i1.z, i1.w};
            const float* wp = s_w + ((kd * 3 + kh) * 3 + kw) * 128 + co;
#pragma unroll
            for (int ci = 0; ci < 8; ci++) {
              float vv = fmaxf(fmaf(r[ci], s_sc[ci], s_bi[ci]), 0.f);
              acc = fmaf(vv, wp[ci * 16], acc);
            }
          } } }
      s2[(size_t)v * 16 + co] = acc;
      sum += acc; sq += acc * acc;
    }
  }
  wreduce<16>(sum, sq);
  if ((t & 63) < 16) { atomicAdd(&s_sum[co], sum); atomicAdd(&s_sq[co], sq); }
  __syncthreads();
  if (t < 16) {
    if (s_sum[t] != 0.f) atomicAdd(&stats[ST_SUM2 + t], s_sum[t]);
    if (s_sq[t]  != 0.f) atomicAdd(&stats[ST_SQ2 + t], s_sq[t]);
  }
}

// ---------- conv3: 32^3 -> 16^3, 16->32 raw; applies BN2+relu inline ----------
__global__ __launch_bounds__(256) void k_conv3(const float* __restrict__ s2raw,
                                               const int* __restrict__ m2,
                                               const int* __restrict__ m4,
                                               const float* __restrict__ w,
                                               const float* __restrict__ g2,
                                               const float* __restrict__ b2,
                                               float* __restrict__ h3,
                                               float* __restrict__ stats) {
  __shared__ float s_w[13824];
  __shared__ float s_sc[16], s_bi[16];
  __shared__ float s_sum[32], s_sq[32];
  int t = threadIdx.x;
  { const float4* w4 = (const float4*)w; float4* sw4 = (float4*)s_w;
    for (int i = t; i < 3456; i += 256) sw4[i] = w4[i]; }
  if (t < 16) {
    float cnt = fmaxf(stats[ST_CNT2], 1.f);
    float mean = stats[ST_SUM2 + t] / cnt;
    float var = fmaxf(stats[ST_SQ2 + t] / cnt - mean * mean, 0.f);
    float sc = g2[t] * rsqrtf(var + EPSBN);
    s_sc[t] = sc; s_bi[t] = b2[t] - mean * sc;
  }
  if (t < 32) { s_sum[t] = 0.f; s_sq[t] = 0.f; }
  __syncthreads();
  int co = t & 31, slot = t >> 5;  // 8 slots
  float sum = 0.f, sq = 0.f;
  for (int it = 0; it < 2; ++it) {
    int v = (it * 512 + blockIdx.x) * 8 + slot;
    if (m4[v]) {
      int vx = v & 15, vy = (v >> 4) & 15, vz = (v >> 8) & 15, vb = v >> 12;
      float acc = 0.f;
      for (int kd = 0; kd < 3; kd++) { int d = 2 * vz + kd - 1; if ((unsigned)d >= 32u) continue;
        for (int kh = 0; kh < 3; kh++) { int h = 2 * vy + kh - 1; if ((unsigned)h >= 32u) continue;
          for (int kw = 0; kw < 3; kw++) { int ww = 2 * vx + kw - 1; if ((unsigned)ww >= 32u) continue;
            int ni = ((vb * 32 + d) * 32 + h) * 32 + ww;
            if (!m2[ni]) continue;
            const float4* ip = (const float4*)(s2raw + (size_t)ni * 16);
            float4 q0 = ip[0], q1 = ip[1], q2 = ip[2], q3 = ip[3];
            float r[16] = {q0.x,q0.y,q0.z,q0.w, q1.x,q1.y,q1.z,q1.w,
                           q2.x,q2.y,q2.z,q2.w, q3.x,q3.y,q3.z,q3.w};
            const float* wp = s_w + ((kd * 3 + kh) * 3 + kw) * 512 + co;
#pragma unroll
            for (int ci = 0; ci < 16; ci++) {
              float vv = fmaxf(fmaf(r[ci], s_sc[ci], s_bi[ci]), 0.f);
              acc = fmaf(vv, wp[ci * 32], acc);
            }
          } } }
      h3[(size_t)v * 32 + co] = acc;
      sum += acc; sq += acc * acc;
    }
  }
  wreduce<32>(sum, sq);
  if ((t & 63) < 32) { atomicAdd(&s_sum[co], sum); atomicAdd(&s_sq[co], sq); }
  __syncthreads();
  if (t < 32) {
    if (s_sum[t] != 0.f) atomicAdd(&stats[ST_SUM3 + t], s_sum[t]);
    if (s_sq[t]  != 0.f) atomicAdd(&stats[ST_SQ3 + t], s_sq[t]);
  }
}

// ---------- convt3: 16^3 -> 32^3, 32->16 raw; applies BN3+relu inline ----------
__global__ __launch_bounds__(256) void k_convt3(const float* __restrict__ h3raw,
                                                const int* __restrict__ m4,
                                                const int* __restrict__ m2,
                                                const float* __restrict__ w,
                                                const float* __restrict__ g3,
                                                const float* __restrict__ b3,
                                                float* __restrict__ t3,
                                                float* __restrict__ stats) {
  __shared__ float s_w[13824];
  __shared__ float s_sc[32], s_bi[32];
  __shared__ float s_sum[16], s_sq[16];
  int t = threadIdx.x;
  { const float4* w4 = (const float4*)w; float4* sw4 = (float4*)s_w;
    for (int i = t; i < 3456; i += 256) sw4[i] = w4[i]; }
  if (t < 32) {
    float cnt = fmaxf(stats[ST_CNT4], 1.f);
    float mean = stats[ST_SUM3 + t] / cnt;
    float var = fmaxf(stats[ST_SQ3 + t] / cnt - mean * mean, 0.f);
    float sc = g3[t] * rsqrtf(var + EPSBN);
    s_sc[t] = sc; s_bi[t] = b3[t] - mean * sc;
  }
  if (t < 16) { s_sum[t] = 0.f; s_sq[t] = 0.f; }
  __syncthreads();
  int co = t & 15, slot = t >> 4;  // 16 slots
  float sum = 0.f, sq = 0.f;
  for (int it = 0; it < 8; ++it) {
    int v = (it * 512 + blockIdx.x) * 16 + slot;
    if (m2[v]) {
      int px = v & 31, py = (v >> 5) & 31, pz = (v >> 10) & 31, vb = v >> 15;
      int cz[2], kz[2], cy[2], ky[2], cx[2], kx[2];
      int nz = taps1d(pz, 16, cz, kz);
      int ny = taps1d(py, 16, cy, ky);
      int nx = taps1d(px, 16, cx, kx);
      float acc = 0.f;
      for (int iz = 0; iz < nz; iz++)
        for (int iy = 0; iy < ny; iy++)
          for (int ix = 0; ix < nx; ix++) {
            int ni = ((vb * 16 + cz[iz]) * 16 + cy[iy]) * 16 + cx[ix];
            if (!m4[ni]) continue;
            const float4* ip = (const float4*)(h3raw + (size_t)ni * 32);
            const float* wp = s_w + ((kz[iz] * 3 + ky[iy]) * 3 + kx[ix]) * 512 + co;
#pragma unroll
            for (int cq = 0; cq < 8; cq++) {
              float4 q = ip[cq];
              float vv;
              vv = fmaxf(fmaf(q.x, s_sc[cq*4+0], s_bi[cq*4+0]), 0.f); acc = fmaf(vv, wp[(cq*4+0)*16], acc);
              vv = fmaxf(fmaf(q.y, s_sc[cq*4+1], s_bi[cq*4+1]), 0.f); acc = fmaf(vv, wp[(cq*4+1)*16], acc);
              vv = fmaxf(fmaf(q.z, s_sc[cq*4+2], s_bi[cq*4+2]), 0.f); acc = fmaf(vv, wp[(cq*4+2)*16], acc);
              vv = fmaxf(fmaf(q.w, s_sc[cq*4+3], s_bi[cq*4+3]), 0.f); acc = fmaf(vv, wp[(cq*4+3)*16], acc);
            }
          }
      t3[(size_t)v * 16 + co] = acc;
      sum += acc; sq += acc * acc;
    }
  }
  wreduce<16>(sum, sq);
  if ((t & 63) < 16) { atomicAdd(&s_sum[co], sum); atomicAdd(&s_sq[co], sq); }
  __syncthreads();
  if (t < 16) {
    if (s_sum[t] != 0.f) atomicAdd(&stats[ST_SUM3T + t], s_sum[t]);
    if (s_sq[t]  != 0.f) atomicAdd(&stats[ST_SQ3T + t], s_sq[t]);
  }
}

// ---------- convt2: 32^3 -> 64^3, concat(bn3t+relu(t3), bn2(s2)) -> 16 raw -> d_out ----------
__global__ __launch_bounds__(256) void k_convt2(const float* __restrict__ t3raw,
                                                const float* __restrict__ s2raw,
                                                const int* __restrict__ m1,
                                                const int* __restrict__ m2,
                                                const float* __restrict__ w,
                                                const float* __restrict__ g3t,
                                                const float* __restrict__ b3t,
                                                const float* __restrict__ g2,
                                                const float* __restrict__ b2,
                                                float* __restrict__ outraw,
                                                float* __restrict__ stats) {
  __shared__ float s_w[13824];
  __shared__ float s_sct[16], s_bit[16], s_sc2[16], s_bi2[16];
  __shared__ float s_sum[16], s_sq[16];
  int t = threadIdx.x;
  { const float4* w4 = (const float4*)w; float4* sw4 = (float4*)s_w;
    for (int i = t; i < 3456; i += 256) sw4[i] = w4[i]; }
  if (t < 16) {
    float cnt = fmaxf(stats[ST_CNT2], 1.f);
    float mean = stats[ST_SUM3T + t] / cnt;
    float var = fmaxf(stats[ST_SQ3T + t] / cnt - mean * mean, 0.f);
    float sc = g3t[t] * rsqrtf(var + EPSBN);
    s_sct[t] = sc; s_bit[t] = b3t[t] - mean * sc;
    float mean2 = stats[ST_SUM2 + t] / cnt;
    float var2 = fmaxf(stats[ST_SQ2 + t] / cnt - mean2 * mean2, 0.f);
    float sc2 = g2[t] * rsqrtf(var2 + EPSBN);
    s_sc2[t] = sc2; s_bi2[t] = b2[t] - mean2 * sc2;
    s_sum[t] = 0.f; s_sq[t] = 0.f;
  }
  __syncthreads();
  int co = t & 15, slot = t >> 4;  // 16 slots
  float sum = 0.f, sq = 0.f;
  for (int it = 0; it < 16; ++it) {
    int v = (it * 2048 + blockIdx.x) * 16 + slot;
    if (m1[v]) {
      int px = v & 63, py = (v >> 6) & 63, pz = (v >> 12) & 63, vb = v >> 18;
      int cz[2], kz[2], cy[2], ky[2], cx[2], kx[2];
      int nz = taps1d(pz, 32, cz, kz);
      int ny = taps1d(py, 32, cy, ky);
      int nx = taps1d(px, 32, cx, kx);
      float acc = 0.f;
      for (int iz = 0; iz < nz; iz++)
        for (int iy = 0; iy < ny; iy++)
          for (int ix = 0; ix < nx; ix++) {
            int ni = ((vb * 32 + cz[iz]) * 32 + cy[iy]) * 32 + cx[ix];
            if (!m2[ni]) continue;
            const float4* tp = (const float4*)(t3raw + (size_t)ni * 16);
            const float4* sp = (const float4*)(s2raw + (size_t)ni * 16);
            const float* wp = s_w + ((kz[iz] * 3 + ky[iy]) * 3 + kx[ix]) * 512 + co;
#pragma unroll
            for (int cq = 0; cq < 4; cq++) {
              float4 q = tp[cq];
              float vv;
              vv = fmaxf(fmaf(q.x, s_sct[cq*4+0], s_bit[cq*4+0]), 0.f); acc = fmaf(vv, wp[(cq*4+0)*16], acc);
              vv = fmaxf(fmaf(q.y, s_sct[cq*4+1], s_bit[cq*4+1]), 0.f); acc = fmaf(vv, wp[(cq*4+1)*16], acc);
              vv = fmaxf(fmaf(q.z, s_sct[cq*4+2], s_bit[cq*4+2]), 0.f); acc = fmaf(vv, wp[(cq*4+2)*16], acc);
              vv = fmaxf(fmaf(q.w, s_sct[cq*4+3], s_bit[cq*4+3]), 0.f); acc = fmaf(vv, wp[(cq*4+3)*16], acc);
            }
#pragma unroll
            for (int cq = 0; cq < 4; cq++) {
              float4 q = sp[cq];
              float vv;
              vv = fmaf(q.x, s_sc2[cq*4+0], s_bi2[cq*4+0]); acc = fmaf(vv, wp[(16+cq*4+0)*16], acc);
              vv = fmaf(q.y, s_sc2[cq*4+1], s_bi2[cq*4+1]); acc = fmaf(vv, wp[(16+cq*4+1)*16], acc);
              vv = fmaf(q.z, s_sc2[cq*4+2], s_bi2[cq*4+2]); acc = fmaf(vv, wp[(16+cq*4+2)*16], acc);
              vv = fmaf(q.w, s_sc2[cq*4+3], s_bi2[cq*4+3]); acc = fmaf(vv, wp[(16+cq*4+3)*16], acc);
            }
          }
      outraw[(size_t)v * 16 + co] = acc;
      sum += acc; sq += acc * acc;
    }
  }
  wreduce<16>(sum, sq);
  if ((t & 63) < 16) { atomicAdd(&s_sum[co], sum); atomicAdd(&s_sq[co], sq); }
  __syncthreads();
  if (t < 16) {
    if (s_sum[t] != 0.f) atomicAdd(&stats[ST_SUM2T + t], s_sum[t]);
    if (s_sq[t]  != 0.f) atomicAdd(&stats[ST_SQ2T + t], s_sq[t]);
  }
}

// ---------- final: BN2t+relu(outraw) concat BN1(h1raw) -> 1x1 conv, mask ----------
__global__ __launch_bounds__(256) void k_final(float* __restrict__ out,
                                               const float* __restrict__ h1raw,
                                               const int* __restrict__ m1,
                                               const float* __restrict__ g2t,
                                               const float* __restrict__ b2t,
                                               const float* __restrict__ g1,
                                               const float* __restrict__ b1,
                                               const float* __restrict__ w1x1,
                                               const float* __restrict__ stats) {
  __shared__ float s_sc[16], s_bi[16], s_sc1[8], s_bi1[8], s_w[384];
  int t = threadIdx.x;
  for (int i = t; i < 384; i += 256) s_w[i] = w1x1[i];
  if (t < 16) {
    float cnt = fmaxf(stats[ST_CNT1], 1.f);
    float mean = stats[ST_SUM2T + t] / cnt;
    float var = fmaxf(stats[ST_SQ2T + t] / cnt - mean * mean, 0.f);
    float sc = g2t[t] * rsqrtf(var + EPSBN);
    s_sc[t] = sc; s_bi[t] = b2t[t] - mean * sc;
  }
  if (t < 8) {
    float cnt = fmaxf(stats[ST_CNT1], 1.f);
    float mean = stats[ST_SUM1 + t] / cnt;
    float var = fmaxf(stats[ST_SQ1 + t] / cnt - mean * mean, 0.f);
    float sc = g1[t] * rsqrtf(var + EPSBN);
    s_sc1[t] = sc; s_bi1[t] = b1[t] - mean * sc;
  }
  __syncthreads();
  int idx = blockIdx.x * 256 + t;
  float* op = out + (size_t)idx * 16;
  if (!m1[idx]) {
    float4 z = {0.f, 0.f, 0.f, 0.f};
    float4* op4 = (float4*)op;
    op4[0] = z; op4[1] = z; op4[2] = z; op4[3] = z;
    return;
  }
  float t2[16];
  {
    const float4* op4 = (const float4*)op;
#pragma unroll
    for (int cq = 0; cq < 4; cq++) {
      float4 q = op4[cq];
      t2[cq*4+0] = fmaxf(fmaf(q.x, s_sc[cq*4+0], s_bi[cq*4+0]), 0.f);
      t2[cq*4+1] = fmaxf(fmaf(q.y, s_sc[cq*4+1], s_bi[cq*4+1]), 0.f);
      t2[cq*4+2] = fmaxf(fmaf(q.z, s_sc[cq*4+2], s_bi[cq*4+2]), 0.f);
      t2[cq*4+3] = fmaxf(fmaf(q.w, s_sc[cq*4+3], s_bi[cq*4+3]), 0.f);
    }
  }
  float s1v[8];
  {
    const float4* sp4 = (const float4*)(h1raw + (size_t)idx * 8);
#pragma unroll
    for (int cq = 0; cq < 2; cq++) {
      float4 q = sp4[cq];
      s1v[cq*4+0] = fmaf(q.x, s_sc1[cq*4+0], s_bi1[cq*4+0]);
      s1v[cq*4+1] = fmaf(q.y, s_sc1[cq*4+1], s_bi1[cq*4+1]);
      s1v[cq*4+2] = fmaf(q.z, s_sc1[cq*4+2], s_bi1[cq*4+2]);
      s1v[cq*4+3] = fmaf(q.w, s_sc1[cq*4+3], s_bi1[cq*4+3]);
    }
  }
  float o[16];
#pragma unroll
  for (int oc = 0; oc < 16; oc++) o[oc] = 0.f;
#pragma unroll
  for (int c = 0; c < 16; c++) {
    float v = t2[c];
#pragma unroll
    for (int oc = 0; oc < 16; oc++) o[oc] = fmaf(v, s_w[c * 16 + oc], o[oc]);
  }
#pragma unroll
  for (int c = 0; c < 8; c++) {
    float v = s1v[c];
#pragma unroll
    for (int oc = 0; oc < 16; oc++) o[oc] = fmaf(v, s_w[(16 + c) * 16 + oc], o[oc]);
  }
  float4* op4 = (float4*)op;
#pragma unroll
  for (int cq = 0; cq < 4; cq++) {
    float4 q = {o[cq*4+0], o[cq*4+1], o[cq*4+2], o[cq*4+3]};
    op4[cq] = q;
  }
}

extern "C" void kernel_launch(void* const* d_in, const int* in_sizes, int n_in,
                              void* d_out, int out_size, void* d_ws, size_t ws_size,
                              hipStream_t stream) {
  const float* x    = (const float*)d_in[0];
  const void*  mraw = d_in[1];
  const float* w1   = (const float*)d_in[2];
  const float* g1   = (const float*)d_in[3];
  const float* b1   = (const float*)d_in[4];
  const float* w2   = (const float*)d_in[5];
  const float* g2   = (const float*)d_in[6];
  const float* b2   = (const float*)d_in[7];
  const float* w3   = (const float*)d_in[8];
  const float* g3   = (const float*)d_in[9];
  const float* b3   = (const float*)d_in[10];
  const float* w3t  = (const float*)d_in[11];
  const float* g3t  = (const float*)d_in[12];
  const float* b3t  = (const float*)d_in[13];
  const float* w2t  = (const float*)d_in[14];
  const float* g2t  = (const float*)d_in[15];
  const float* b2t  = (const float*)d_in[16];
  const float* w1x1 = (const float*)d_in[17];

  float* ws = (float*)d_ws;
  float* stats = ws;
  int* flags = (int*)(ws + FLAG_OFF);
  int* m1c = (int*)(ws + OFF_M1C);
  int* m2  = (int*)(ws + OFF_M2);
  int* m4  = (int*)(ws + OFF_M4);
  float* h1 = ws + OFF_H1;
  float* s2 = ws + OFF_S2;
  float* h3 = ws + OFF_H3;
  float* t3 = ws + OFF_T3;
  float* out = (float*)d_out;

  hipMemsetAsync(ws, 0, ST_ZERO * sizeof(float), stream);
  k_detect<<<256, 256, 0, stream>>>((const unsigned int*)mraw, flags);
  k_canon<<<NVOX1 / 256, 256, 0, stream>>>(mraw, m1c, flags);
  k_down1<<<NVOX2 / 256, 256, 0, stream>>>(m1c, m2, stats);
  k_down2<<<NVOX4 / 256, 256, 0, stream>>>(m2, m4, stats);
  k_conv1<<<2048, 256, 0, stream>>>(x, m1c, w1, h1, stats);
  k_conv2<<<2048, 256, 0, stream>>>(h1, m1c, m2, w2, g1, b1, s2, stats);
  k_conv3<<<512, 256, 0, stream>>>(s2, m2, m4, w3, g2, b2, h3, stats);
  k_convt3<<<512, 256, 0, stream>>>(h3, m4, m2, w3t, g3, b3, t3, stats);
  k_convt2<<<2048, 256, 0, stream>>>(t3, s2, m1c, m2, w2t, g3t, b3t, g2, b2, out, stats);
  k_final<<<NVOX1 / 256, 256, 0, stream>>>(out, h1, m1c, g2t, b2t, g1, b1, w1x1, stats);
}

// Round 3
// 338.058 us; speedup vs baseline: 1.5655x; 1.2732x over previous
//
#include <hip/hip_runtime.h>

#define NVOX1 524288   // 2*64^3
#define NVOX2 65536    // 2*32^3
#define NVOX4 8192     // 2*16^3

// float offsets into ws (stats area, zeroed each launch)
#define ST_SUM1 16
#define ST_SQ1  24
#define ST_SUM2 32
#define ST_SQ2  48
#define ST_SUM3 64
#define ST_SQ3  96
#define ST_SUM3T 128
#define ST_SQ3T  144
#define ST_SUM2T 160
#define ST_SQ2T  176
#define FLAG_OFF 200   // 2 ints
#define IC_N1 204      // int counters (double as BN counts)
#define IC_N2 205
#define IC_N4 206
#define ST_ZERO 256    // floats memset to 0 each launch

// buffer offsets (in floats)
#define OFF_M1C 512
#define OFF_M2  (OFF_M1C + NVOX1)
#define OFF_M4  (OFF_M2 + NVOX2)
#define OFF_H1  (OFF_M4 + NVOX4)
#define OFF_S2  (OFF_H1 + NVOX1 * 8)
#define OFF_H3  (OFF_S2 + NVOX2 * 16)
#define OFF_T3  (OFF_H3 + NVOX4 * 32)
#define OFF_L1  (OFF_T3 + NVOX2 * 16)
#define OFF_L2  (OFF_L1 + NVOX1)
#define OFF_L4  (OFF_L2 + NVOX2)

#define EPSBN 1e-5f

// ---------- helpers ----------
template <int C>
__device__ __forceinline__ void wreduce(float& a, float& b) {
#pragma unroll
  for (int off = C; off < 64; off <<= 1) {
    a += __shfl_xor(a, off, 64);
    b += __shfl_xor(b, off, 64);
  }
}

__device__ __forceinline__ int taps1d(int p, int gin, int* c, int* k) {
  if ((p & 1) == 0) { c[0] = p >> 1; k[0] = 1; return 1; }
  int n = 0;
  c[n] = (p - 1) >> 1; k[n] = 0; n++;
  int c2 = (p + 1) >> 1;
  if (c2 < gin) { c[n] = c2; k[n] = 2; n++; }
  return n;
}

// wave-aggregated compact-list append
__device__ __forceinline__ void wave_append(int* cnt, int* list, int idx, int active) {
  unsigned long long b = __ballot(active != 0);
  if (active) {
    int lane = threadIdx.x & 63;
    int pre = __popcll(b & ((1ull << lane) - 1ull));
    int leader = __ffsll((unsigned long long)b) - 1;
    int base = 0;
    if (lane == leader) base = atomicAdd(cnt, __popcll(b));
    base = __shfl(base, leader, 64);
    list[base + pre] = idx;
  }
}

// ---------- mask format detection & canonicalization + list1 ----------
__global__ __launch_bounds__(256) void k_detect(const unsigned int* __restrict__ m,
                                                int* __restrict__ flags) {
  int tid = blockIdx.x * 256 + threadIdx.x;
  int hasf = 0, hasb = 0;
  for (int i = tid; i < NVOX1; i += 256 * 256) {
    unsigned int v = m[i];
    if (v == 0x3F800000u) hasf = 1;
    else if (v > 1u) hasb = 1;
  }
  hasf = __syncthreads_or(hasf);
  hasb = __syncthreads_or(hasb);
  if (threadIdx.x == 0) {
    if (hasf) atomicOr(&flags[0], 1);
    if (hasb) atomicOr(&flags[1], 1);
  }
}

__global__ __launch_bounds__(256) void k_canon(const void* __restrict__ mraw,
                                               int* __restrict__ m1c,
                                               const int* __restrict__ flags,
                                               int* __restrict__ cnts,
                                               int* __restrict__ list1) {
  int idx = blockIdx.x * 256 + threadIdx.x;
  if (idx >= NVOX1) return;
  int isf = flags[0], isb = flags[1];
  int v;
  if (isf)      v = (((const float*)mraw)[idx] != 0.f);
  else if (isb) v = (((const unsigned char*)mraw)[idx] != 0);
  else          v = (((const int*)mraw)[idx] != 0);
  m1c[idx] = v;
  wave_append(&cnts[IC_N1], list1, idx, v);
}

// ---------- mask downsampling + lists ----------
__global__ __launch_bounds__(256) void k_down1(const int* __restrict__ m1,
                                               int* __restrict__ m2,
                                               int* __restrict__ cnts,
                                               int* __restrict__ list2) {
  int idx = blockIdx.x * 256 + threadIdx.x;
  int x = idx & 31, y = (idx >> 5) & 31, z = (idx >> 10) & 31, b = idx >> 15;
  int any = 0;
#pragma unroll
  for (int dz = 0; dz < 2; dz++)
#pragma unroll
    for (int dy = 0; dy < 2; dy++)
#pragma unroll
      for (int dx = 0; dx < 2; dx++)
        any |= m1[((b * 64 + 2 * z + dz) * 64 + 2 * y + dy) * 64 + 2 * x + dx];
  m2[idx] = any ? 1 : 0;
  wave_append(&cnts[IC_N2], list2, idx, any);
}

__global__ __launch_bounds__(256) void k_down2(const int* __restrict__ m2,
                                               int* __restrict__ m4,
                                               int* __restrict__ cnts,
                                               int* __restrict__ list4) {
  int idx = blockIdx.x * 256 + threadIdx.x;
  int x = idx & 15, y = (idx >> 4) & 15, z = (idx >> 8) & 15, b = idx >> 12;
  int any = 0;
#pragma unroll
  for (int dz = 0; dz < 2; dz++)
#pragma unroll
    for (int dy = 0; dy < 2; dy++)
#pragma unroll
      for (int dx = 0; dx < 2; dx++)
        any |= m2[((b * 32 + 2 * z + dz) * 32 + 2 * y + dy) * 32 + 2 * x + dx];
  m4[idx] = any ? 1 : 0;
  wave_append(&cnts[IC_N4], list4, idx, any);
}

// ---------- conv1: 4->8 raw over list1, item=(voxel,co) ----------
__global__ __launch_bounds__(256) void k_conv1(const float* __restrict__ x,
                                               const int* __restrict__ m1,
                                               const int* __restrict__ list1,
                                               const int* __restrict__ cnts,
                                               const float* __restrict__ w,
                                               float* __restrict__ h1,
                                               float* __restrict__ stats) {
  __shared__ float s_w[27 * 36];
  __shared__ float s_sum[8], s_sq[8];
  int t = threadIdx.x;
  { const float4* w4 = (const float4*)w;
    for (int i = t; i < 216; i += 256) {
      int flat = i * 4, tap = flat >> 5, rem = flat & 31;
      *(float4*)(s_w + tap * 36 + rem) = w4[i];
    } }
  if (t < 8) { s_sum[t] = 0.f; s_sq[t] = 0.f; }
  __syncthreads();
  int items = cnts[IC_N1] * 8;
  float sum = 0.f, sq = 0.f;
  for (int i = blockIdx.x * 256 + t; i < items; i += gridDim.x * 256) {
    int li = i >> 3, co = i & 7;
    int v = list1[li];
    int vx = v & 63, vy = (v >> 6) & 63, vz = (v >> 12) & 63, vb = v >> 18;
    float a0 = 0.f, a1 = 0.f;
    for (int kd = 0; kd < 3; kd++) { int d = vz + kd - 1; if ((unsigned)d >= 64u) continue;
      for (int kh = 0; kh < 3; kh++) { int h = vy + kh - 1; if ((unsigned)h >= 64u) continue;
        for (int kw = 0; kw < 3; kw++) { int ww = vx + kw - 1; if ((unsigned)ww >= 64u) continue;
          int ni = ((vb * 64 + d) * 64 + h) * 64 + ww;
          if (!m1[ni]) continue;
          float4 ip = *(const float4*)(x + (size_t)ni * 4);
          const float* wp = s_w + ((kd * 3 + kh) * 3 + kw) * 36 + co;
          a0 = fmaf(ip.x, wp[0], a0);
          a1 = fmaf(ip.y, wp[8], a1);
          a0 = fmaf(ip.z, wp[16], a0);
          a1 = fmaf(ip.w, wp[24], a1);
        } } }
    float acc = a0 + a1;
    h1[(size_t)v * 8 + co] = acc;
    sum += acc; sq += acc * acc;
  }
  wreduce<8>(sum, sq);
  if ((t & 63) < 8) { atomicAdd(&s_sum[t & 7], sum); atomicAdd(&s_sq[t & 7], sq); }
  __syncthreads();
  if (t < 8) {
    if (s_sum[t] != 0.f) atomicAdd(&stats[ST_SUM1 + t], s_sum[t]);
    if (s_sq[t]  != 0.f) atomicAdd(&stats[ST_SQ1 + t], s_sq[t]);
  }
}

// ---------- conv2: 8->16 raw over list2; BN1+relu inline ----------
__global__ __launch_bounds__(256) void k_conv2(const float* __restrict__ h1,
                                               const int* __restrict__ m1,
                                               const int* __restrict__ list2,
                                               const int* __restrict__ cnts,
                                               const float* __restrict__ w,
                                               const float* __restrict__ g1,
                                               const float* __restrict__ b1,
                                               float* __restrict__ s2,
                                               float* __restrict__ stats) {
  __shared__ float s_w[27 * 132];
  __shared__ float s_sc[8], s_bi[8];
  __shared__ float s_sum[16], s_sq[16];
  int t = threadIdx.x;
  { const float4* w4 = (const float4*)w;
    for (int i = t; i < 864; i += 256) {
      int flat = i * 4, tap = flat >> 7, rem = flat & 127;
      *(float4*)(s_w + tap * 132 + rem) = w4[i];
    } }
  if (t < 8) {
    float cnt = fmaxf((float)cnts[IC_N1], 1.f);
    float mean = stats[ST_SUM1 + t] / cnt;
    float var = fmaxf(stats[ST_SQ1 + t] / cnt - mean * mean, 0.f);
    float sc = g1[t] * rsqrtf(var + EPSBN);
    s_sc[t] = sc; s_bi[t] = b1[t] - mean * sc;
  }
  if (t < 16) { s_sum[t] = 0.f; s_sq[t] = 0.f; }
  __syncthreads();
  int items = cnts[IC_N2] * 16;
  float sum = 0.f, sq = 0.f;
  for (int i = blockIdx.x * 256 + t; i < items; i += gridDim.x * 256) {
    int li = i >> 4, co = i & 15;
    int v = list2[li];
    int vx = v & 31, vy = (v >> 5) & 31, vz = (v >> 10) & 31, vb = v >> 15;
    float a0 = 0.f, a1 = 0.f;
    for (int kd = 0; kd < 3; kd++) { int d = 2 * vz + kd - 1; if ((unsigned)d >= 64u) continue;
      for (int kh = 0; kh < 3; kh++) { int h = 2 * vy + kh - 1; if ((unsigned)h >= 64u) continue;
        for (int kw = 0; kw < 3; kw++) { int ww = 2 * vx + kw - 1; if ((unsigned)ww >= 64u) continue;
          int ni = ((vb * 64 + d) * 64 + h) * 64 + ww;
          if (!m1[ni]) continue;
          float4 i0 = *(const float4*)(h1 + (size_t)ni * 8);
          float4 i1 = *(const float4*)(h1 + (size_t)ni * 8 + 4);
          const float* wp = s_w + ((kd * 3 + kh) * 3 + kw) * 132 + co;
          float vv;
          vv = fmaxf(fmaf(i0.x, s_sc[0], s_bi[0]), 0.f); a0 = fmaf(vv, wp[0 * 16], a0);
          vv = fmaxf(fmaf(i0.y, s_sc[1], s_bi[1]), 0.f); a1 = fmaf(vv, wp[1 * 16], a1);
          vv = fmaxf(fmaf(i0.z, s_sc[2], s_bi[2]), 0.f); a0 = fmaf(vv, wp[2 * 16], a0);
          vv = fmaxf(fmaf(i0.w, s_sc[3], s_bi[3]), 0.f); a1 = fmaf(vv, wp[3 * 16], a1);
          vv = fmaxf(fmaf(i1.x, s_sc[4], s_bi[4]), 0.f); a0 = fmaf(vv, wp[4 * 16], a0);
          vv = fmaxf(fmaf(i1.y, s_sc[5], s_bi[5]), 0.f); a1 = fmaf(vv, wp[5 * 16], a1);
          vv = fmaxf(fmaf(i1.z, s_sc[6], s_bi[6]), 0.f); a0 = fmaf(vv, wp[6 * 16], a0);
          vv = fmaxf(fmaf(i1.w, s_sc[7], s_bi[7]), 0.f); a1 = fmaf(vv, wp[7 * 16], a1);
        } } }
    float acc = a0 + a1;
    s2[(size_t)v * 16 + co] = acc;
    sum += acc; sq += acc * acc;
  }
  wreduce<16>(sum, sq);
  if ((t & 63) < 16) { atomicAdd(&s_sum[t & 15], sum); atomicAdd(&s_sq[t & 15], sq); }
  __syncthreads();
  if (t < 16) {
    if (s_sum[t] != 0.f) atomicAdd(&stats[ST_SUM2 + t], s_sum[t]);
    if (s_sq[t]  != 0.f) atomicAdd(&stats[ST_SQ2 + t], s_sq[t]);
  }
}

// ---------- conv3: 16->32 raw over list4; BN2+relu inline ----------
__global__ __launch_bounds__(512) void k_conv3(const float* __restrict__ s2raw,
                                               const int* __restrict__ m2,
                                               const int* __restrict__ list4,
                                               const int* __restrict__ cnts,
                                               const float* __restrict__ w,
                                               const float* __restrict__ g2,
                                               const float* __restrict__ b2,
                                               float* __restrict__ h3,
                                               float* __restrict__ stats) {
  __shared__ float s_w[27 * 516];
  __shared__ float s_sc[16], s_bi[16];
  __shared__ float s_sum[32], s_sq[32];
  int t = threadIdx.x;
  { const float4* w4 = (const float4*)w;
    for (int i = t; i < 3456; i += 512) {
      int flat = i * 4, tap = flat >> 9, rem = flat & 511;
      *(float4*)(s_w + tap * 516 + rem) = w4[i];
    } }
  if (t < 16) {
    float cnt = fmaxf((float)cnts[IC_N2], 1.f);
    float mean = stats[ST_SUM2 + t] / cnt;
    float var = fmaxf(stats[ST_SQ2 + t] / cnt - mean * mean, 0.f);
    float sc = g2[t] * rsqrtf(var + EPSBN);
    s_sc[t] = sc; s_bi[t] = b2[t] - mean * sc;
  }
  if (t < 32) { s_sum[t] = 0.f; s_sq[t] = 0.f; }
  __syncthreads();
  int items = cnts[IC_N4] * 32;
  float sum = 0.f, sq = 0.f;
  for (int i = blockIdx.x * 512 + t; i < items; i += gridDim.x * 512) {
    int li = i >> 5, co = i & 31;
    int v = list4[li];
    int vx = v & 15, vy = (v >> 4) & 15, vz = (v >> 8) & 15, vb = v >> 12;
    float ac[4] = {0.f, 0.f, 0.f, 0.f};
    for (int kd = 0; kd < 3; kd++) { int d = 2 * vz + kd - 1; if ((unsigned)d >= 32u) continue;
      for (int kh = 0; kh < 3; kh++) { int h = 2 * vy + kh - 1; if ((unsigned)h >= 32u) continue;
        for (int kw = 0; kw < 3; kw++) { int ww = 2 * vx + kw - 1; if ((unsigned)ww >= 32u) continue;
          int ni = ((vb * 32 + d) * 32 + h) * 32 + ww;
          if (!m2[ni]) continue;
          const float4* ip = (const float4*)(s2raw + (size_t)ni * 16);
          const float* wp = s_w + ((kd * 3 + kh) * 3 + kw) * 516 + co;
#pragma unroll
          for (int cq = 0; cq < 4; cq++) {
            float4 q = ip[cq];
            float vv;
            vv = fmaxf(fmaf(q.x, s_sc[cq * 4 + 0], s_bi[cq * 4 + 0]), 0.f); ac[0] = fmaf(vv, wp[(cq * 4 + 0) * 32], ac[0]);
            vv = fmaxf(fmaf(q.y, s_sc[cq * 4 + 1], s_bi[cq * 4 + 1]), 0.f); ac[1] = fmaf(vv, wp[(cq * 4 + 1) * 32], ac[1]);
            vv = fmaxf(fmaf(q.z, s_sc[cq * 4 + 2], s_bi[cq * 4 + 2]), 0.f); ac[2] = fmaf(vv, wp[(cq * 4 + 2) * 32], ac[2]);
            vv = fmaxf(fmaf(q.w, s_sc[cq * 4 + 3], s_bi[cq * 4 + 3]), 0.f); ac[3] = fmaf(vv, wp[(cq * 4 + 3) * 32], ac[3]);
          }
        } } }
    float acc = (ac[0] + ac[1]) + (ac[2] + ac[3]);
    h3[(size_t)v * 32 + co] = acc;
    sum += acc; sq += acc * acc;
  }
  wreduce<32>(sum, sq);
  if ((t & 63) < 32) { atomicAdd(&s_sum[t & 31], sum); atomicAdd(&s_sq[t & 31], sq); }
  __syncthreads();
  if (t < 32) {
    if (s_sum[t] != 0.f) atomicAdd(&stats[ST_SUM3 + t], s_sum[t]);
    if (s_sq[t]  != 0.f) atomicAdd(&stats[ST_SQ3 + t], s_sq[t]);
  }
}

// ---------- convt3: 32->16 raw over list2; BN3+relu inline ----------
__global__ __launch_bounds__(512) void k_convt3(const float* __restrict__ h3raw,
                                                const int* __restrict__ m4,
                                                const int* __restrict__ list2,
                                                const int* __restrict__ cnts,
                                                const float* __restrict__ w,
                                                const float* __restrict__ g3,
                                                const float* __restrict__ b3,
                                                float* __restrict__ t3,
                                                float* __restrict__ stats) {
  __shared__ float s_w[27 * 516];
  __shared__ float s_sc[32], s_bi[32];
  __shared__ float s_sum[16], s_sq[16];
  int t = threadIdx.x;
  { const float4* w4 = (const float4*)w;
    for (int i = t; i < 3456; i += 512) {
      int flat = i * 4, tap = flat >> 9, rem = flat & 511;
      *(float4*)(s_w + tap * 516 + rem) = w4[i];
    } }
  if (t < 32) {
    float cnt = fmaxf((float)cnts[IC_N4], 1.f);
    float mean = stats[ST_SUM3 + t] / cnt;
    float var = fmaxf(stats[ST_SQ3 + t] / cnt - mean * mean, 0.f);
    float sc = g3[t] * rsqrtf(var + EPSBN);
    s_sc[t] = sc; s_bi[t] = b3[t] - mean * sc;
  }
  if (t < 16) { s_sum[t] = 0.f; s_sq[t] = 0.f; }
  __syncthreads();
  int items = cnts[IC_N2] * 16;
  float sum = 0.f, sq = 0.f;
  for (int i = blockIdx.x * 512 + t; i < items; i += gridDim.x * 512) {
    int li = i >> 4, co = i & 15;
    int v = list2[li];
    int px = v & 31, py = (v >> 5) & 31, pz = (v >> 10) & 31, vb = v >> 15;
    int cz[2], kz[2], cy[2], ky[2], cx[2], kx[2];
    int nz = taps1d(pz, 16, cz, kz);
    int ny = taps1d(py, 16, cy, ky);
    int nx = taps1d(px, 16, cx, kx);
    float ac[4] = {0.f, 0.f, 0.f, 0.f};
    for (int iz = 0; iz < nz; iz++)
      for (int iy = 0; iy < ny; iy++)
        for (int ix = 0; ix < nx; ix++) {
          int ni = ((vb * 16 + cz[iz]) * 16 + cy[iy]) * 16 + cx[ix];
          if (!m4[ni]) continue;
          const float4* ip = (const float4*)(h3raw + (size_t)ni * 32);
          const float* wp = s_w + ((kz[iz] * 3 + ky[iy]) * 3 + kx[ix]) * 516 + co;
#pragma unroll
          for (int cq = 0; cq < 8; cq++) {
            float4 q = ip[cq];
            float vv;
            vv = fmaxf(fmaf(q.x, s_sc[cq * 4 + 0], s_bi[cq * 4 + 0]), 0.f); ac[0] = fmaf(vv, wp[(cq * 4 + 0) * 16], ac[0]);
            vv = fmaxf(fmaf(q.y, s_sc[cq * 4 + 1], s_bi[cq * 4 + 1]), 0.f); ac[1] = fmaf(vv, wp[(cq * 4 + 1) * 16], ac[1]);
            vv = fmaxf(fmaf(q.z, s_sc[cq * 4 + 2], s_bi[cq * 4 + 2]), 0.f); ac[2] = fmaf(vv, wp[(cq * 4 + 2) * 16], ac[2]);
            vv = fmaxf(fmaf(q.w, s_sc[cq * 4 + 3], s_bi[cq * 4 + 3]), 0.f); ac[3] = fmaf(vv, wp[(cq * 4 + 3) * 16], ac[3]);
          }
        }
    float acc = (ac[0] + ac[1]) + (ac[2] + ac[3]);
    t3[(size_t)v * 16 + co] = acc;
    sum += acc; sq += acc * acc;
  }
  wreduce<16>(sum, sq);
  if ((t & 63) < 16) { atomicAdd(&s_sum[t & 15], sum); atomicAdd(&s_sq[t & 15], sq); }
  __syncthreads();
  if (t < 16) {
    if (s_sum[t] != 0.f) atomicAdd(&stats[ST_SUM3T + t], s_sum[t]);
    if (s_sq[t]  != 0.f) atomicAdd(&stats[ST_SQ3T + t], s_sq[t]);
  }
}

// ---------- convt2: concat(bn3t+relu(t3), bn2(s2)) -> 16 raw -> d_out, over list1 ----------
__global__ __launch_bounds__(512) void k_convt2(const float* __restrict__ t3raw,
                                                const float* __restrict__ s2raw,
                                                const int* __restrict__ m2,
                                                const int* __restrict__ list1,
                                                const int* __restrict__ cnts,
                                                const float* __restrict__ w,
                                                const float* __restrict__ g3t,
                                                const float* __restrict__ b3t,
                                                const float* __restrict__ g2,
                                                const float* __restrict__ b2,
                                                float* __restrict__ outraw,
                                                float* __restrict__ stats) {
  __shared__ float s_w[27 * 516];
  __shared__ float s_sct[16], s_bit[16], s_sc2[16], s_bi2[16];
  __shared__ float s_sum[16], s_sq[16];
  int t = threadIdx.x;
  { const float4* w4 = (const float4*)w;
    for (int i = t; i < 3456; i += 512) {
      int flat = i * 4, tap = flat >> 9, rem = flat & 511;
      *(float4*)(s_w + tap * 516 + rem) = w4[i];
    } }
  if (t < 16) {
    float cnt = fmaxf((float)cnts[IC_N2], 1.f);
    float mean = stats[ST_SUM3T + t] / cnt;
    float var = fmaxf(stats[ST_SQ3T + t] / cnt - mean * mean, 0.f);
    float sc = g3t[t] * rsqrtf(var + EPSBN);
    s_sct[t] = sc; s_bit[t] = b3t[t] - mean * sc;
    float mean2 = stats[ST_SUM2 + t] / cnt;
    float var2 = fmaxf(stats[ST_SQ2 + t] / cnt - mean2 * mean2, 0.f);
    float sc2 = g2[t] * rsqrtf(var2 + EPSBN);
    s_sc2[t] = sc2; s_bi2[t] = b2[t] - mean2 * sc2;
    s_sum[t] = 0.f; s_sq[t] = 0.f;
  }
  __syncthreads();
  int items = cnts[IC_N1] * 16;
  float sum = 0.f, sq = 0.f;
  for (int i = blockIdx.x * 512 + t; i < items; i += gridDim.x * 512) {
    int li = i >> 4, co = i & 15;
    int v = list1[li];
    int px = v & 63, py = (v >> 6) & 63, pz = (v >> 12) & 63, vb = v >> 18;
    int cz[2], kz[2], cy[2], ky[2], cx[2], kx[2];
    int nz = taps1d(pz, 32, cz, kz);
    int ny = taps1d(py, 32, cy, ky);
    int nx = taps1d(px, 32, cx, kx);
    float ac[4] = {0.f, 0.f, 0.f, 0.f};
    for (int iz = 0; iz < nz; iz++)
      for (int iy = 0; iy < ny; iy++)
        for (int ix = 0; ix < nx; ix++) {
          int ni = ((vb * 32 + cz[iz]) * 32 + cy[iy]) * 32 + cx[ix];
          if (!m2[ni]) continue;
          const float4* tp = (const float4*)(t3raw + (size_t)ni * 16);
          const float4* sp = (const float4*)(s2raw + (size_t)ni * 16);
          const float* wp = s_w + ((kz[iz] * 3 + ky[iy]) * 3 + kx[ix]) * 516 + co;
#pragma unroll
          for (int cq = 0; cq < 4; cq++) {
            float4 q = tp[cq];
            float vv;
            vv = fmaxf(fmaf(q.x, s_sct[cq * 4 + 0], s_bit[cq * 4 + 0]), 0.f); ac[0] = fmaf(vv, wp[(cq * 4 + 0) * 16], ac[0]);
            vv = fmaxf(fmaf(q.y, s_sct[cq * 4 + 1], s_bit[cq * 4 + 1]), 0.f); ac[1] = fmaf(vv, wp[(cq * 4 + 1) * 16], ac[1]);
            vv = fmaxf(fmaf(q.z, s_sct[cq * 4 + 2], s_bit[cq * 4 + 2]), 0.f); ac[2] = fmaf(vv, wp[(cq * 4 + 2) * 16], ac[2]);
            vv = fmaxf(fmaf(q.w, s_sct[cq * 4 + 3], s_bit[cq * 4 + 3]), 0.f); ac[3] = fmaf(vv, wp[(cq * 4 + 3) * 16], ac[3]);
          }
#pragma unroll
          for (int cq = 0; cq < 4; cq++) {
            float4 q = sp[cq];
            float vv;
            vv = fmaf(q.x, s_sc2[cq * 4 + 0], s_bi2[cq * 4 + 0]); ac[0] = fmaf(vv, wp[(16 + cq * 4 + 0) * 16], ac[0]);
            vv = fmaf(q.y, s_sc2[cq * 4 + 1], s_bi2[cq * 4 + 1]); ac[1] = fmaf(vv, wp[(16 + cq * 4 + 1) * 16], ac[1]);
            vv = fmaf(q.z, s_sc2[cq * 4 + 2], s_bi2[cq * 4 + 2]); ac[2] = fmaf(vv, wp[(16 + cq * 4 + 2) * 16], ac[2]);
            vv = fmaf(q.w, s_sc2[cq * 4 + 3], s_bi2[cq * 4 + 3]); ac[3] = fmaf(vv, wp[(16 + cq * 4 + 3) * 16], ac[3]);
          }
        }
    float acc = (ac[0] + ac[1]) + (ac[2] + ac[3]);
    outraw[(size_t)v * 16 + co] = acc;
    sum += acc; sq += acc * acc;
  }
  wreduce<16>(sum, sq);
  if ((t & 63) < 16) { atomicAdd(&s_sum[t & 15], sum); atomicAdd(&s_sq[t & 15], sq); }
  __syncthreads();
  if (t < 16) {
    if (s_sum[t] != 0.f) atomicAdd(&stats[ST_SUM2T + t], s_sum[t]);
    if (s_sq[t]  != 0.f) atomicAdd(&stats[ST_SQ2T + t], s_sq[t]);
  }
}

// ---------- final: BN2t+relu(out) concat BN1(h1) -> 1x1, sparse in-place per voxel ----------
__global__ __launch_bounds__(256) void k_final(float* __restrict__ out,
                                               const float* __restrict__ h1raw,
                                               const int* __restrict__ list1,
                                               const int* __restrict__ cnts,
                                               const float* __restrict__ g2t,
                                               const float* __restrict__ b2t,
                                               const float* __restrict__ g1,
                                               const float* __restrict__ b1,
                                               const float* __restrict__ w1x1,
                                               const float* __restrict__ stats) {
  __shared__ float s_sc[16], s_bi[16], s_sc1[8], s_bi1[8], s_w[384];
  int t = threadIdx.x;
  for (int i = t; i < 384; i += 256) s_w[i] = w1x1[i];
  if (t < 16) {
    float cnt = fmaxf((float)cnts[IC_N1], 1.f);
    float mean = stats[ST_SUM2T + t] / cnt;
    float var = fmaxf(stats[ST_SQ2T + t] / cnt - mean * mean, 0.f);
    float sc = g2t[t] * rsqrtf(var + EPSBN);
    s_sc[t] = sc; s_bi[t] = b2t[t] - mean * sc;
  }
  if (t < 8) {
    float cnt = fmaxf((float)cnts[IC_N1], 1.f);
    float mean = stats[ST_SUM1 + t] / cnt;
    float var = fmaxf(stats[ST_SQ1 + t] / cnt - mean * mean, 0.f);
    float sc = g1[t] * rsqrtf(var + EPSBN);
    s_sc1[t] = sc; s_bi1[t] = b1[t] - mean * sc;
  }
  __syncthreads();
  int n = cnts[IC_N1];
  for (int i = blockIdx.x * 256 + t; i < n; i += gridDim.x * 256) {
    int v = list1[i];
    float* op = out + (size_t)v * 16;
    float t2[16];
    {
      const float4* op4 = (const float4*)op;
#pragma unroll
      for (int cq = 0; cq < 4; cq++) {
        float4 q = op4[cq];
        t2[cq * 4 + 0] = fmaxf(fmaf(q.x, s_sc[cq * 4 + 0], s_bi[cq * 4 + 0]), 0.f);
        t2[cq * 4 + 1] = fmaxf(fmaf(q.y, s_sc[cq * 4 + 1], s_bi[cq * 4 + 1]), 0.f);
        t2[cq * 4 + 2] = fmaxf(fmaf(q.z, s_sc[cq * 4 + 2], s_bi[cq * 4 + 2]), 0.f);
        t2[cq * 4 + 3] = fmaxf(fmaf(q.w, s_sc[cq * 4 + 3], s_bi[cq * 4 + 3]), 0.f);
      }
    }
    float s1v[8];
    {
      const float4* sp4 = (const float4*)(h1raw + (size_t)v * 8);
#pragma unroll
      for (int cq = 0; cq < 2; cq++) {
        float4 q = sp4[cq];
        s1v[cq * 4 + 0] = fmaf(q.x, s_sc1[cq * 4 + 0], s_bi1[cq * 4 + 0]);
        s1v[cq * 4 + 1] = fmaf(q.y, s_sc1[cq * 4 + 1], s_bi1[cq * 4 + 1]);
        s1v[cq * 4 + 2] = fmaf(q.z, s_sc1[cq * 4 + 2], s_bi1[cq * 4 + 2]);
        s1v[cq * 4 + 3] = fmaf(q.w, s_sc1[cq * 4 + 3], s_bi1[cq * 4 + 3]);
      }
    }
    float o[16];
#pragma unroll
    for (int oc = 0; oc < 16; oc++) o[oc] = 0.f;
#pragma unroll
    for (int c = 0; c < 16; c++) {
      float vv = t2[c];
#pragma unroll
      for (int oc = 0; oc < 16; oc++) o[oc] = fmaf(vv, s_w[c * 16 + oc], o[oc]);
    }
#pragma unroll
    for (int c = 0; c < 8; c++) {
      float vv = s1v[c];
#pragma unroll
      for (int oc = 0; oc < 16; oc++) o[oc] = fmaf(vv, s_w[(16 + c) * 16 + oc], o[oc]);
    }
    float4* op4 = (float4*)op;
#pragma unroll
    for (int cq = 0; cq < 4; cq++) {
      float4 q = {o[cq * 4 + 0], o[cq * 4 + 1], o[cq * 4 + 2], o[cq * 4 + 3]};
      op4[cq] = q;
    }
  }
}

extern "C" void kernel_launch(void* const* d_in, const int* in_sizes, int n_in,
                              void* d_out, int out_size, void* d_ws, size_t ws_size,
                              hipStream_t stream) {
  const float* x    = (const float*)d_in[0];
  const void*  mraw = d_in[1];
  const float* w1   = (const float*)d_in[2];
  const float* g1   = (const float*)d_in[3];
  const float* b1   = (const float*)d_in[4];
  const float* w2   = (const float*)d_in[5];
  const float* g2   = (const float*)d_in[6];
  const float* b2   = (const float*)d_in[7];
  const float* w3   = (const float*)d_in[8];
  const float* g3   = (const float*)d_in[9];
  const float* b3   = (const float*)d_in[10];
  const float* w3t  = (const float*)d_in[11];
  const float* g3t  = (const float*)d_in[12];
  const float* b3t  = (const float*)d_in[13];
  const float* w2t  = (const float*)d_in[14];
  const float* g2t  = (const float*)d_in[15];
  const float* b2t  = (const float*)d_in[16];
  const float* w1x1 = (const float*)d_in[17];

  float* ws = (float*)d_ws;
  float* stats = ws;
  int* cnts = (int*)ws;
  int* flags = (int*)(ws + FLAG_OFF);
  int* m1c = (int*)(ws + OFF_M1C);
  int* m2  = (int*)(ws + OFF_M2);
  int* m4  = (int*)(ws + OFF_M4);
  float* h1 = ws + OFF_H1;
  float* s2 = ws + OFF_S2;
  float* h3 = ws + OFF_H3;
  float* t3 = ws + OFF_T3;
  int* list1 = (int*)(ws + OFF_L1);
  int* list2 = (int*)(ws + OFF_L2);
  int* list4 = (int*)(ws + OFF_L4);
  float* out = (float*)d_out;

  hipMemsetAsync(ws, 0, ST_ZERO * sizeof(float), stream);
  hipMemsetAsync(d_out, 0, (size_t)out_size * sizeof(float), stream);
  k_detect<<<256, 256, 0, stream>>>((const unsigned int*)mraw, flags);
  k_canon<<<NVOX1 / 256, 256, 0, stream>>>(mraw, m1c, flags, cnts, list1);
  k_down1<<<NVOX2 / 256, 256, 0, stream>>>(m1c, m2, cnts, list2);
  k_down2<<<NVOX4 / 256, 256, 0, stream>>>(m2, m4, cnts, list4);
  k_conv1<<<1024, 256, 0, stream>>>(x, m1c, list1, cnts, w1, h1, stats);
  k_conv2<<<1024, 256, 0, stream>>>(h1, m1c, list2, cnts, w2, g1, b1, s2, stats);
  k_conv3<<<512, 512, 0, stream>>>(s2, m2, list4, cnts, w3, g2, b2, h3, stats);
  k_convt3<<<512, 512, 0, stream>>>(h3, m4, list2, cnts, w3t, g3, b3, t3, stats);
  k_convt2<<<512, 512, 0, stream>>>(t3, s2, m2, list1, cnts, w2t, g3t, b3t, g2, b2, out, stats);
  k_final<<<256, 256, 0, stream>>>(out, h1, list1, cnts, g2t, b2t, g1, b1, w1x1, stats);
}

// Round 4
// 238.722 us; speedup vs baseline: 2.2169x; 1.4161x over previous
//
#include <hip/hip_runtime.h>

#define NVOX1 524288   // 2*64^3
#define NVOX2 65536    // 2*32^3
#define NVOX4 8192     // 2*16^3

// float offsets into ws (stats area, zeroed each launch)
#define ST_SUM1 16
#define ST_SQ1  24
#define ST_SUM2 32
#define ST_SQ2  48
#define ST_SUM3 64
#define ST_SQ3  96
#define ST_SUM3T 128
#define ST_SQ3T  144
#define ST_SUM2T 160
#define ST_SQ2T  176
#define FLAG_OFF 200   // 2 ints
#define IC_N1 204      // int counters (double as BN counts)
#define IC_N2 205
#define IC_N4 206
#define ST_ZERO 256    // floats memset to 0 each launch

// buffer offsets (in floats)
#define OFF_M1C 512
#define OFF_M2  (OFF_M1C + NVOX1)
#define OFF_M4  (OFF_M2 + NVOX2)
#define OFF_H1  (OFF_M4 + NVOX4)
#define OFF_S2  (OFF_H1 + NVOX1 * 8)
#define OFF_H3  (OFF_S2 + NVOX2 * 16)
#define OFF_T3  (OFF_H3 + NVOX4 * 32)
#define OFF_L1  (OFF_T3 + NVOX2 * 16)
#define OFF_L2  (OFF_L1 + NVOX1)
#define OFF_L4  (OFF_L2 + NVOX2)
#define OFF_BC1 (OFF_L4 + NVOX4)   // 2048 ints: per-block counts -> bases (level 1)
#define OFF_BC2 (OFF_BC1 + 2048)   // 256 ints (level 2)
#define OFF_BC4 (OFF_BC2 + 256)    // 32 ints (level 4)

#define EPSBN 1e-5f

// ---------- helpers ----------
template <int C>
__device__ __forceinline__ void wreduce(float& a, float& b) {
#pragma unroll
  for (int off = C; off < 64; off <<= 1) {
    a += __shfl_xor(a, off, 64);
    b += __shfl_xor(b, off, 64);
  }
}

__device__ __forceinline__ int taps1d(int p, int gin, int* c, int* k) {
  if ((p & 1) == 0) { c[0] = p >> 1; k[0] = 1; return 1; }
  int n = 0;
  c[n] = (p - 1) >> 1; k[n] = 0; n++;
  int c2 = (p + 1) >> 1;
  if (c2 < gin) { c[n] = c2; k[n] = 2; n++; }
  return n;
}

// ---------- mask format detection ----------
__global__ __launch_bounds__(256) void k_detect(const unsigned int* __restrict__ m,
                                                int* __restrict__ flags) {
  int tid = blockIdx.x * 256 + threadIdx.x;
  int hasf = 0, hasb = 0;
  for (int i = tid; i < NVOX1; i += 256 * 256) {
    unsigned int v = m[i];
    if (v == 0x3F800000u) hasf = 1;
    else if (v > 1u) hasb = 1;
  }
  hasf = __syncthreads_or(hasf);
  hasb = __syncthreads_or(hasb);
  if (threadIdx.x == 0) {
    if (hasf) atomicOr(&flags[0], 1);
    if (hasb) atomicOr(&flags[1], 1);
  }
}

// ---------- canonicalize mask + per-block count (NO atomics) ----------
__global__ __launch_bounds__(256) void k_canon(const void* __restrict__ mraw,
                                               int* __restrict__ m1c,
                                               const int* __restrict__ flags,
                                               int* __restrict__ blkcnt1) {
  int idx = blockIdx.x * 256 + threadIdx.x;
  int isf = flags[0], isb = flags[1];
  int v;
  if (isf)      v = (((const float*)mraw)[idx] != 0.f);
  else if (isb) v = (((const unsigned char*)mraw)[idx] != 0);
  else          v = (((const int*)mraw)[idx] != 0);
  m1c[idx] = v;
  int c = __syncthreads_count(v);
  if (threadIdx.x == 0) blkcnt1[blockIdx.x] = c;
}

// ---------- mask downsampling + per-block counts ----------
__global__ __launch_bounds__(256) void k_down1(const int* __restrict__ m1,
                                               int* __restrict__ m2,
                                               int* __restrict__ blkcnt2) {
  int idx = blockIdx.x * 256 + threadIdx.x;
  int x = idx & 31, y = (idx >> 5) & 31, z = (idx >> 10) & 31, b = idx >> 15;
  int any = 0;
#pragma unroll
  for (int dz = 0; dz < 2; dz++)
#pragma unroll
    for (int dy = 0; dy < 2; dy++)
#pragma unroll
      for (int dx = 0; dx < 2; dx++)
        any |= m1[((b * 64 + 2 * z + dz) * 64 + 2 * y + dy) * 64 + 2 * x + dx];
  any = any ? 1 : 0;
  m2[idx] = any;
  int c = __syncthreads_count(any);
  if (threadIdx.x == 0) blkcnt2[blockIdx.x] = c;
}

__global__ __launch_bounds__(256) void k_down2(const int* __restrict__ m2,
                                               int* __restrict__ m4,
                                               int* __restrict__ blkcnt4) {
  int idx = blockIdx.x * 256 + threadIdx.x;
  int x = idx & 15, y = (idx >> 4) & 15, z = (idx >> 8) & 15, b = idx >> 12;
  int any = 0;
#pragma unroll
  for (int dz = 0; dz < 2; dz++)
#pragma unroll
    for (int dy = 0; dy < 2; dy++)
#pragma unroll
      for (int dx = 0; dx < 2; dx++)
        any |= m2[((b * 32 + 2 * z + dz) * 32 + 2 * y + dy) * 32 + 2 * x + dx];
  any = any ? 1 : 0;
  m4[idx] = any;
  int c = __syncthreads_count(any);
  if (threadIdx.x == 0) blkcnt4[blockIdx.x] = c;
}

// ---------- scan: per-block counts -> exclusive bases (in place) + totals ----------
__global__ __launch_bounds__(1024) void k_scan(int* __restrict__ bc1,
                                               int* __restrict__ bc2,
                                               int* __restrict__ bc4,
                                               int* __restrict__ cnts) {
  __shared__ int sA[2048], sB[2048];
  int* a; int n; int outIdx;
  if (blockIdx.x == 0)      { a = bc1; n = 2048; outIdx = IC_N1; }
  else if (blockIdx.x == 1) { a = bc2; n = 256;  outIdx = IC_N2; }
  else                      { a = bc4; n = 32;   outIdx = IC_N4; }
  int t = threadIdx.x;
  int i0 = t, i1 = t + 1024;
  int v0 = (i0 < n) ? a[i0] : 0;
  int v1 = (i1 < n) ? a[i1] : 0;
  sA[i0] = v0; sA[i1] = v1;
  __syncthreads();
  int* src = sA; int* dst = sB;
  for (int st = 1; st < 2048; st <<= 1) {
    int x0 = src[i0]; if (i0 >= st) x0 += src[i0 - st];
    int x1 = src[i1]; if (i1 >= st) x1 += src[i1 - st];
    dst[i0] = x0; dst[i1] = x1;
    __syncthreads();
    int* tmp = src; src = dst; dst = tmp;
  }
  // src = inclusive scan over padded 2048 (pads are 0)
  if (i0 < n) a[i0] = src[i0] - v0;
  if (i1 < n) a[i1] = src[i1] - v1;
  if (t == 0) cnts[outIdx] = src[2047];
}

// ---------- scatter: deterministic sorted compact lists (all 3 levels fused) ----------
__global__ __launch_bounds__(256) void k_scatter(const int* __restrict__ m1,
                                                 const int* __restrict__ m2,
                                                 const int* __restrict__ m4,
                                                 const int* __restrict__ bc1,
                                                 const int* __restrict__ bc2,
                                                 const int* __restrict__ bc4,
                                                 int* __restrict__ list1,
                                                 int* __restrict__ list2,
                                                 int* __restrict__ list4) {
  __shared__ int s_w[4];
  int bid = blockIdx.x, t = threadIdx.x;
  const int* mask; const int* base; int* list; int lb;
  if (bid < 2048)      { mask = m1; base = bc1; list = list1; lb = bid; }
  else if (bid < 2304) { mask = m2; base = bc2; list = list2; lb = bid - 2048; }
  else                 { mask = m4; base = bc4; list = list4; lb = bid - 2304; }
  int idx = lb * 256 + t;
  int act = mask[idx];
  unsigned long long b = __ballot(act != 0);
  int lane = t & 63, wid = t >> 6;
  if (lane == 0) s_w[wid] = __popcll(b);
  __syncthreads();
  int wbase = 0;
  for (int i = 0; i < wid; i++) wbase += s_w[i];
  if (act) {
    int pre = __popcll(b & ((1ull << lane) - 1ull));
    list[base[lb] + wbase + pre] = idx;
  }
}

// ---------- conv1: 4->8 raw over list1, item=(voxel,co) ----------
__global__ __launch_bounds__(256) void k_conv1(const float* __restrict__ x,
                                               const int* __restrict__ m1,
                                               const int* __restrict__ list1,
                                               const int* __restrict__ cnts,
                                               const float* __restrict__ w,
                                               float* __restrict__ h1,
                                               float* __restrict__ stats) {
  __shared__ float s_w[27 * 36];
  __shared__ float s_sum[8], s_sq[8];
  int t = threadIdx.x;
  { const float4* w4 = (const float4*)w;
    for (int i = t; i < 216; i += 256) {
      int flat = i * 4, tap = flat >> 5, rem = flat & 31;
      *(float4*)(s_w + tap * 36 + rem) = w4[i];
    } }
  if (t < 8) { s_sum[t] = 0.f; s_sq[t] = 0.f; }
  __syncthreads();
  int items = cnts[IC_N1] * 8;
  float sum = 0.f, sq = 0.f;
  for (int i = blockIdx.x * 256 + t; i < items; i += gridDim.x * 256) {
    int li = i >> 3, co = i & 7;
    int v = list1[li];
    int vx = v & 63, vy = (v >> 6) & 63, vz = (v >> 12) & 63, vb = v >> 18;
    float a0 = 0.f, a1 = 0.f;
    for (int kd = 0; kd < 3; kd++) { int d = vz + kd - 1; if ((unsigned)d >= 64u) continue;
      for (int kh = 0; kh < 3; kh++) { int h = vy + kh - 1; if ((unsigned)h >= 64u) continue;
        for (int kw = 0; kw < 3; kw++) { int ww = vx + kw - 1; if ((unsigned)ww >= 64u) continue;
          int ni = ((vb * 64 + d) * 64 + h) * 64 + ww;
          if (!m1[ni]) continue;
          float4 ip = *(const float4*)(x + (size_t)ni * 4);
          const float* wp = s_w + ((kd * 3 + kh) * 3 + kw) * 36 + co;
          a0 = fmaf(ip.x, wp[0], a0);
          a1 = fmaf(ip.y, wp[8], a1);
          a0 = fmaf(ip.z, wp[16], a0);
          a1 = fmaf(ip.w, wp[24], a1);
        } } }
    float acc = a0 + a1;
    h1[(size_t)v * 8 + co] = acc;
    sum += acc; sq += acc * acc;
  }
  wreduce<8>(sum, sq);
  if ((t & 63) < 8) { atomicAdd(&s_sum[t & 7], sum); atomicAdd(&s_sq[t & 7], sq); }
  __syncthreads();
  if (t < 8) {
    if (s_sum[t] != 0.f) atomicAdd(&stats[ST_SUM1 + t], s_sum[t]);
    if (s_sq[t]  != 0.f) atomicAdd(&stats[ST_SQ1 + t], s_sq[t]);
  }
}

// ---------- conv2: 8->16 raw over list2; BN1+relu inline ----------
__global__ __launch_bounds__(256) void k_conv2(const float* __restrict__ h1,
                                               const int* __restrict__ m1,
                                               const int* __restrict__ list2,
                                               const int* __restrict__ cnts,
                                               const float* __restrict__ w,
                                               const float* __restrict__ g1,
                                               const float* __restrict__ b1,
                                               float* __restrict__ s2,
                                               float* __restrict__ stats) {
  __shared__ float s_w[27 * 132];
  __shared__ float s_sc[8], s_bi[8];
  __shared__ float s_sum[16], s_sq[16];
  int t = threadIdx.x;
  { const float4* w4 = (const float4*)w;
    for (int i = t; i < 864; i += 256) {
      int flat = i * 4, tap = flat >> 7, rem = flat & 127;
      *(float4*)(s_w + tap * 132 + rem) = w4[i];
    } }
  if (t < 8) {
    float cnt = fmaxf((float)cnts[IC_N1], 1.f);
    float mean = stats[ST_SUM1 + t] / cnt;
    float var = fmaxf(stats[ST_SQ1 + t] / cnt - mean * mean, 0.f);
    float sc = g1[t] * rsqrtf(var + EPSBN);
    s_sc[t] = sc; s_bi[t] = b1[t] - mean * sc;
  }
  if (t < 16) { s_sum[t] = 0.f; s_sq[t] = 0.f; }
  __syncthreads();
  int items = cnts[IC_N2] * 16;
  float sum = 0.f, sq = 0.f;
  for (int i = blockIdx.x * 256 + t; i < items; i += gridDim.x * 256) {
    int li = i >> 4, co = i & 15;
    int v = list2[li];
    int vx = v & 31, vy = (v >> 5) & 31, vz = (v >> 10) & 31, vb = v >> 15;
    float a0 = 0.f, a1 = 0.f;
    for (int kd = 0; kd < 3; kd++) { int d = 2 * vz + kd - 1; if ((unsigned)d >= 64u) continue;
      for (int kh = 0; kh < 3; kh++) { int h = 2 * vy + kh - 1; if ((unsigned)h >= 64u) continue;
        for (int kw = 0; kw < 3; kw++) { int ww = 2 * vx + kw - 1; if ((unsigned)ww >= 64u) continue;
          int ni = ((vb * 64 + d) * 64 + h) * 64 + ww;
          if (!m1[ni]) continue;
          float4 i0 = *(const float4*)(h1 + (size_t)ni * 8);
          float4 i1 = *(const float4*)(h1 + (size_t)ni * 8 + 4);
          const float* wp = s_w + ((kd * 3 + kh) * 3 + kw) * 132 + co;
          float vv;
          vv = fmaxf(fmaf(i0.x, s_sc[0], s_bi[0]), 0.f); a0 = fmaf(vv, wp[0 * 16], a0);
          vv = fmaxf(fmaf(i0.y, s_sc[1], s_bi[1]), 0.f); a1 = fmaf(vv, wp[1 * 16], a1);
          vv = fmaxf(fmaf(i0.z, s_sc[2], s_bi[2]), 0.f); a0 = fmaf(vv, wp[2 * 16], a0);
          vv = fmaxf(fmaf(i0.w, s_sc[3], s_bi[3]), 0.f); a1 = fmaf(vv, wp[3 * 16], a1);
          vv = fmaxf(fmaf(i1.x, s_sc[4], s_bi[4]), 0.f); a0 = fmaf(vv, wp[4 * 16], a0);
          vv = fmaxf(fmaf(i1.y, s_sc[5], s_bi[5]), 0.f); a1 = fmaf(vv, wp[5 * 16], a1);
          vv = fmaxf(fmaf(i1.z, s_sc[6], s_bi[6]), 0.f); a0 = fmaf(vv, wp[6 * 16], a0);
          vv = fmaxf(fmaf(i1.w, s_sc[7], s_bi[7]), 0.f); a1 = fmaf(vv, wp[7 * 16], a1);
        } } }
    float acc = a0 + a1;
    s2[(size_t)v * 16 + co] = acc;
    sum += acc; sq += acc * acc;
  }
  wreduce<16>(sum, sq);
  if ((t & 63) < 16) { atomicAdd(&s_sum[t & 15], sum); atomicAdd(&s_sq[t & 15], sq); }
  __syncthreads();
  if (t < 16) {
    if (s_sum[t] != 0.f) atomicAdd(&stats[ST_SUM2 + t], s_sum[t]);
    if (s_sq[t]  != 0.f) atomicAdd(&stats[ST_SQ2 + t], s_sq[t]);
  }
}

// ---------- conv3: 16->32 raw over list4; BN2+relu inline ----------
__global__ __launch_bounds__(512) void k_conv3(const float* __restrict__ s2raw,
                                               const int* __restrict__ m2,
                                               const int* __restrict__ list4,
                                               const int* __restrict__ cnts,
                                               const float* __restrict__ w,
                                               const float* __restrict__ g2,
                                               const float* __restrict__ b2,
                                               float* __restrict__ h3,
                                               float* __restrict__ stats) {
  __shared__ float s_w[27 * 516];
  __shared__ float s_sc[16], s_bi[16];
  __shared__ float s_sum[32], s_sq[32];
  int t = threadIdx.x;
  { const float4* w4 = (const float4*)w;
    for (int i = t; i < 3456; i += 512) {
      int flat = i * 4, tap = flat >> 9, rem = flat & 511;
      *(float4*)(s_w + tap * 516 + rem) = w4[i];
    } }
  if (t < 16) {
    float cnt = fmaxf((float)cnts[IC_N2], 1.f);
    float mean = stats[ST_SUM2 + t] / cnt;
    float var = fmaxf(stats[ST_SQ2 + t] / cnt - mean * mean, 0.f);
    float sc = g2[t] * rsqrtf(var + EPSBN);
    s_sc[t] = sc; s_bi[t] = b2[t] - mean * sc;
  }
  if (t < 32) { s_sum[t] = 0.f; s_sq[t] = 0.f; }
  __syncthreads();
  int items = cnts[IC_N4] * 32;
  float sum = 0.f, sq = 0.f;
  for (int i = blockIdx.x * 512 + t; i < items; i += gridDim.x * 512) {
    int li = i >> 5, co = i & 31;
    int v = list4[li];
    int vx = v & 15, vy = (v >> 4) & 15, vz = (v >> 8) & 15, vb = v >> 12;
    float ac[4] = {0.f, 0.f, 0.f, 0.f};
    for (int kd = 0; kd < 3; kd++) { int d = 2 * vz + kd - 1; if ((unsigned)d >= 32u) continue;
      for (int kh = 0; kh < 3; kh++) { int h = 2 * vy + kh - 1; if ((unsigned)h >= 32u) continue;
        for (int kw = 0; kw < 3; kw++) { int ww = 2 * vx + kw - 1; if ((unsigned)ww >= 32u) continue;
          int ni = ((vb * 32 + d) * 32 + h) * 32 + ww;
          if (!m2[ni]) continue;
          const float4* ip = (const float4*)(s2raw + (size_t)ni * 16);
          const float* wp = s_w + ((kd * 3 + kh) * 3 + kw) * 516 + co;
#pragma unroll
          for (int cq = 0; cq < 4; cq++) {
            float4 q = ip[cq];
            float vv;
            vv = fmaxf(fmaf(q.x, s_sc[cq * 4 + 0], s_bi[cq * 4 + 0]), 0.f); ac[0] = fmaf(vv, wp[(cq * 4 + 0) * 32], ac[0]);
            vv = fmaxf(fmaf(q.y, s_sc[cq * 4 + 1], s_bi[cq * 4 + 1]), 0.f); ac[1] = fmaf(vv, wp[(cq * 4 + 1) * 32], ac[1]);
            vv = fmaxf(fmaf(q.z, s_sc[cq * 4 + 2], s_bi[cq * 4 + 2]), 0.f); ac[2] = fmaf(vv, wp[(cq * 4 + 2) * 32], ac[2]);
            vv = fmaxf(fmaf(q.w, s_sc[cq * 4 + 3], s_bi[cq * 4 + 3]), 0.f); ac[3] = fmaf(vv, wp[(cq * 4 + 3) * 32], ac[3]);
          }
        } } }
    float acc = (ac[0] + ac[1]) + (ac[2] + ac[3]);
    h3[(size_t)v * 32 + co] = acc;
    sum += acc; sq += acc * acc;
  }
  wreduce<32>(sum, sq);
  if ((t & 63) < 32) { atomicAdd(&s_sum[t & 31], sum); atomicAdd(&s_sq[t & 31], sq); }
  __syncthreads();
  if (t < 32) {
    if (s_sum[t] != 0.f) atomicAdd(&stats[ST_SUM3 + t], s_sum[t]);
    if (s_sq[t]  != 0.f) atomicAdd(&stats[ST_SQ3 + t], s_sq[t]);
  }
}

// ---------- convt3: 32->16 raw over list2; BN3+relu inline ----------
__global__ __launch_bounds__(512) void k_convt3(const float* __restrict__ h3raw,
                                                const int* __restrict__ m4,
                                                const int* __restrict__ list2,
                                                const int* __restrict__ cnts,
                                                const float* __restrict__ w,
                                                const float* __restrict__ g3,
                                                const float* __restrict__ b3,
                                                float* __restrict__ t3,
                                                float* __restrict__ stats) {
  __shared__ float s_w[27 * 516];
  __shared__ float s_sc[32], s_bi[32];
  __shared__ float s_sum[16], s_sq[16];
  int t = threadIdx.x;
  { const float4* w4 = (const float4*)w;
    for (int i = t; i < 3456; i += 512) {
      int flat = i * 4, tap = flat >> 9, rem = flat & 511;
      *(float4*)(s_w + tap * 516 + rem) = w4[i];
    } }
  if (t < 32) {
    float cnt = fmaxf((float)cnts[IC_N4], 1.f);
    float mean = stats[ST_SUM3 + t] / cnt;
    float var = fmaxf(stats[ST_SQ3 + t] / cnt - mean * mean, 0.f);
    float sc = g3[t] * rsqrtf(var + EPSBN);
    s_sc[t] = sc; s_bi[t] = b3[t] - mean * sc;
  }
  if (t < 16) { s_sum[t] = 0.f; s_sq[t] = 0.f; }
  __syncthreads();
  int items = cnts[IC_N2] * 16;
  float sum = 0.f, sq = 0.f;
  for (int i = blockIdx.x * 512 + t; i < items; i += gridDim.x * 512) {
    int li = i >> 4, co = i & 15;
    int v = list2[li];
    int px = v & 31, py = (v >> 5) & 31, pz = (v >> 10) & 31, vb = v >> 15;
    int cz[2], kz[2], cy[2], ky[2], cx[2], kx[2];
    int nz = taps1d(pz, 16, cz, kz);
    int ny = taps1d(py, 16, cy, ky);
    int nx = taps1d(px, 16, cx, kx);
    float ac[4] = {0.f, 0.f, 0.f, 0.f};
    for (int iz = 0; iz < nz; iz++)
      for (int iy = 0; iy < ny; iy++)
        for (int ix = 0; ix < nx; ix++) {
          int ni = ((vb * 16 + cz[iz]) * 16 + cy[iy]) * 16 + cx[ix];
          if (!m4[ni]) continue;
          const float4* ip = (const float4*)(h3raw + (size_t)ni * 32);
          const float* wp = s_w + ((kz[iz] * 3 + ky[iy]) * 3 + kx[ix]) * 516 + co;
#pragma unroll
          for (int cq = 0; cq < 8; cq++) {
            float4 q = ip[cq];
            float vv;
            vv = fmaxf(fmaf(q.x, s_sc[cq * 4 + 0], s_bi[cq * 4 + 0]), 0.f); ac[0] = fmaf(vv, wp[(cq * 4 + 0) * 16], ac[0]);
            vv = fmaxf(fmaf(q.y, s_sc[cq * 4 + 1], s_bi[cq * 4 + 1]), 0.f); ac[1] = fmaf(vv, wp[(cq * 4 + 1) * 16], ac[1]);
            vv = fmaxf(fmaf(q.z, s_sc[cq * 4 + 2], s_bi[cq * 4 + 2]), 0.f); ac[2] = fmaf(vv, wp[(cq * 4 + 2) * 16], ac[2]);
            vv = fmaxf(fmaf(q.w, s_sc[cq * 4 + 3], s_bi[cq * 4 + 3]), 0.f); ac[3] = fmaf(vv, wp[(cq * 4 + 3) * 16], ac[3]);
          }
        }
    float acc = (ac[0] + ac[1]) + (ac[2] + ac[3]);
    t3[(size_t)v * 16 + co] = acc;
    sum += acc; sq += acc * acc;
  }
  wreduce<16>(sum, sq);
  if ((t & 63) < 16) { atomicAdd(&s_sum[t & 15], sum); atomicAdd(&s_sq[t & 15], sq); }
  __syncthreads();
  if (t < 16) {
    if (s_sum[t] != 0.f) atomicAdd(&stats[ST_SUM3T + t], s_sum[t]);
    if (s_sq[t]  != 0.f) atomicAdd(&stats[ST_SQ3T + t], s_sq[t]);
  }
}

// ---------- convt2: concat(bn3t+relu(t3), bn2(s2)) -> 16 raw -> d_out, over list1 ----------
__global__ __launch_bounds__(512) void k_convt2(const float* __restrict__ t3raw,
                                                const float* __restrict__ s2raw,
                                                const int* __restrict__ m2,
                                                const int* __restrict__ list1,
                                                const int* __restrict__ cnts,
                                                const float* __restrict__ w,
                                                const float* __restrict__ g3t,
                                                const float* __restrict__ b3t,
                                                const float* __restrict__ g2,
                                                const float* __restrict__ b2,
                                                float* __restrict__ outraw,
                                                float* __restrict__ stats) {
  __shared__ float s_w[27 * 516];
  __shared__ float s_sct[16], s_bit[16], s_sc2[16], s_bi2[16];
  __shared__ float s_sum[16], s_sq[16];
  int t = threadIdx.x;
  { const float4* w4 = (const float4*)w;
    for (int i = t; i < 3456; i += 512) {
      int flat = i * 4, tap = flat >> 9, rem = flat & 511;
      *(float4*)(s_w + tap * 516 + rem) = w4[i];
    } }
  if (t < 16) {
    float cnt = fmaxf((float)cnts[IC_N2], 1.f);
    float mean = stats[ST_SUM3T + t] / cnt;
    float var = fmaxf(stats[ST_SQ3T + t] / cnt - mean * mean, 0.f);
    float sc = g3t[t] * rsqrtf(var + EPSBN);
    s_sct[t] = sc; s_bit[t] = b3t[t] - mean * sc;
    float mean2 = stats[ST_SUM2 + t] / cnt;
    float var2 = fmaxf(stats[ST_SQ2 + t] / cnt - mean2 * mean2, 0.f);
    float sc2 = g2[t] * rsqrtf(var2 + EPSBN);
    s_sc2[t] = sc2; s_bi2[t] = b2[t] - mean2 * sc2;
    s_sum[t] = 0.f; s_sq[t] = 0.f;
  }
  __syncthreads();
  int items = cnts[IC_N1] * 16;
  float sum = 0.f, sq = 0.f;
  for (int i = blockIdx.x * 512 + t; i < items; i += gridDim.x * 512) {
    int li = i >> 4, co = i & 15;
    int v = list1[li];
    int px = v & 63, py = (v >> 6) & 63, pz = (v >> 12) & 63, vb = v >> 18;
    int cz[2], kz[2], cy[2], ky[2], cx[2], kx[2];
    int nz = taps1d(pz, 32, cz, kz);
    int ny = taps1d(py, 32, cy, ky);
    int nx = taps1d(px, 32, cx, kx);
    float ac[4] = {0.f, 0.f, 0.f, 0.f};
    for (int iz = 0; iz < nz; iz++)
      for (int iy = 0; iy < ny; iy++)
        for (int ix = 0; ix < nx; ix++) {
          int ni = ((vb * 32 + cz[iz]) * 32 + cy[iy]) * 32 + cx[ix];
          if (!m2[ni]) continue;
          const float4* tp = (const float4*)(t3raw + (size_t)ni * 16);
          const float4* sp = (const float4*)(s2raw + (size_t)ni * 16);
          const float* wp = s_w + ((kz[iz] * 3 + ky[iy]) * 3 + kx[ix]) * 516 + co;
#pragma unroll
          for (int cq = 0; cq < 4; cq++) {
            float4 q = tp[cq];
            float vv;
            vv = fmaxf(fmaf(q.x, s_sct[cq * 4 + 0], s_bit[cq * 4 + 0]), 0.f); ac[0] = fmaf(vv, wp[(cq * 4 + 0) * 16], ac[0]);
            vv = fmaxf(fmaf(q.y, s_sct[cq * 4 + 1], s_bit[cq * 4 + 1]), 0.f); ac[1] = fmaf(vv, wp[(cq * 4 + 1) * 16], ac[1]);
            vv = fmaxf(fmaf(q.z, s_sct[cq * 4 + 2], s_bit[cq * 4 + 2]), 0.f); ac[2] = fmaf(vv, wp[(cq * 4 + 2) * 16], ac[2]);
            vv = fmaxf(fmaf(q.w, s_sct[cq * 4 + 3], s_bit[cq * 4 + 3]), 0.f); ac[3] = fmaf(vv, wp[(cq * 4 + 3) * 16], ac[3]);
          }
#pragma unroll
          for (int cq = 0; cq < 4; cq++) {
            float4 q = sp[cq];
            float vv;
            vv = fmaf(q.x, s_sc2[cq * 4 + 0], s_bi2[cq * 4 + 0]); ac[0] = fmaf(vv, wp[(16 + cq * 4 + 0) * 16], ac[0]);
            vv = fmaf(q.y, s_sc2[cq * 4 + 1], s_bi2[cq * 4 + 1]); ac[1] = fmaf(vv, wp[(16 + cq * 4 + 1) * 16], ac[1]);
            vv = fmaf(q.z, s_sc2[cq * 4 + 2], s_bi2[cq * 4 + 2]); ac[2] = fmaf(vv, wp[(16 + cq * 4 + 2) * 16], ac[2]);
            vv = fmaf(q.w, s_sc2[cq * 4 + 3], s_bi2[cq * 4 + 3]); ac[3] = fmaf(vv, wp[(16 + cq * 4 + 3) * 16], ac[3]);
          }
        }
    float acc = (ac[0] + ac[1]) + (ac[2] + ac[3]);
    outraw[(size_t)v * 16 + co] = acc;
    sum += acc; sq += acc * acc;
  }
  wreduce<16>(sum, sq);
  if ((t & 63) < 16) { atomicAdd(&s_sum[t & 15], sum); atomicAdd(&s_sq[t & 15], sq); }
  __syncthreads();
  if (t < 16) {
    if (s_sum[t] != 0.f) atomicAdd(&stats[ST_SUM2T + t], s_sum[t]);
    if (s_sq[t]  != 0.f) atomicAdd(&stats[ST_SQ2T + t], s_sq[t]);
  }
}

// ---------- final: BN2t+relu(out) concat BN1(h1) -> 1x1, sparse in-place per voxel ----------
__global__ __launch_bounds__(256) void k_final(float* __restrict__ out,
                                               const float* __restrict__ h1raw,
                                               const int* __restrict__ list1,
                                               const int* __restrict__ cnts,
                                               const float* __restrict__ g2t,
                                               const float* __restrict__ b2t,
                                               const float* __restrict__ g1,
                                               const float* __restrict__ b1,
                                               const float* __restrict__ w1x1,
                                               const float* __restrict__ stats) {
  __shared__ float s_sc[16], s_bi[16], s_sc1[8], s_bi1[8], s_w[384];
  int t = threadIdx.x;
  for (int i = t; i < 384; i += 256) s_w[i] = w1x1[i];
  if (t < 16) {
    float cnt = fmaxf((float)cnts[IC_N1], 1.f);
    float mean = stats[ST_SUM2T + t] / cnt;
    float var = fmaxf(stats[ST_SQ2T + t] / cnt - mean * mean, 0.f);
    float sc = g2t[t] * rsqrtf(var + EPSBN);
    s_sc[t] = sc; s_bi[t] = b2t[t] - mean * sc;
  }
  if (t < 8) {
    float cnt = fmaxf((float)cnts[IC_N1], 1.f);
    float mean = stats[ST_SUM1 + t] / cnt;
    float var = fmaxf(stats[ST_SQ1 + t] / cnt - mean * mean, 0.f);
    float sc = g1[t] * rsqrtf(var + EPSBN);
    s_sc1[t] = sc; s_bi1[t] = b1[t] - mean * sc;
  }
  __syncthreads();
  int n = cnts[IC_N1];
  for (int i = blockIdx.x * 256 + t; i < n; i += gridDim.x * 256) {
    int v = list1[i];
    float* op = out + (size_t)v * 16;
    float t2[16];
    {
      const float4* op4 = (const float4*)op;
#pragma unroll
      for (int cq = 0; cq < 4; cq++) {
        float4 q = op4[cq];
        t2[cq * 4 + 0] = fmaxf(fmaf(q.x, s_sc[cq * 4 + 0], s_bi[cq * 4 + 0]), 0.f);
        t2[cq * 4 + 1] = fmaxf(fmaf(q.y, s_sc[cq * 4 + 1], s_bi[cq * 4 + 1]), 0.f);
        t2[cq * 4 + 2] = fmaxf(fmaf(q.z, s_sc[cq * 4 + 2], s_bi[cq * 4 + 2]), 0.f);
        t2[cq * 4 + 3] = fmaxf(fmaf(q.w, s_sc[cq * 4 + 3], s_bi[cq * 4 + 3]), 0.f);
      }
    }
    float s1v[8];
    {
      const float4* sp4 = (const float4*)(h1raw + (size_t)v * 8);
#pragma unroll
      for (int cq = 0; cq < 2; cq++) {
        float4 q = sp4[cq];
        s1v[cq * 4 + 0] = fmaf(q.x, s_sc1[cq * 4 + 0], s_bi1[cq * 4 + 0]);
        s1v[cq * 4 + 1] = fmaf(q.y, s_sc1[cq * 4 + 1], s_bi1[cq * 4 + 1]);
        s1v[cq * 4 + 2] = fmaf(q.z, s_sc1[cq * 4 + 2], s_bi1[cq * 4 + 2]);
        s1v[cq * 4 + 3] = fmaf(q.w, s_sc1[cq * 4 + 3], s_bi1[cq * 4 + 3]);
      }
    }
    float o[16];
#pragma unroll
    for (int oc = 0; oc < 16; oc++) o[oc] = 0.f;
#pragma unroll
    for (int c = 0; c < 16; c++) {
      float vv = t2[c];
#pragma unroll
      for (int oc = 0; oc < 16; oc++) o[oc] = fmaf(vv, s_w[c * 16 + oc], o[oc]);
    }
#pragma unroll
    for (int c = 0; c < 8; c++) {
      float vv = s1v[c];
#pragma unroll
      for (int oc = 0; oc < 16; oc++) o[oc] = fmaf(vv, s_w[(16 + c) * 16 + oc], o[oc]);
    }
    float4* op4 = (float4*)op;
#pragma unroll
    for (int cq = 0; cq < 4; cq++) {
      float4 q = {o[cq * 4 + 0], o[cq * 4 + 1], o[cq * 4 + 2], o[cq * 4 + 3]};
      op4[cq] = q;
    }
  }
}

extern "C" void kernel_launch(void* const* d_in, const int* in_sizes, int n_in,
                              void* d_out, int out_size, void* d_ws, size_t ws_size,
                              hipStream_t stream) {
  const float* x    = (const float*)d_in[0];
  const void*  mraw = d_in[1];
  const float* w1   = (const float*)d_in[2];
  const float* g1   = (const float*)d_in[3];
  const float* b1   = (const float*)d_in[4];
  const float* w2   = (const float*)d_in[5];
  const float* g2   = (const float*)d_in[6];
  const float* b2   = (const float*)d_in[7];
  const float* w3   = (const float*)d_in[8];
  const float* g3   = (const float*)d_in[9];
  const float* b3   = (const float*)d_in[10];
  const float* w3t  = (const float*)d_in[11];
  const float* g3t  = (const float*)d_in[12];
  const float* b3t  = (const float*)d_in[13];
  const float* w2t  = (const float*)d_in[14];
  const float* g2t  = (const float*)d_in[15];
  const float* b2t  = (const float*)d_in[16];
  const float* w1x1 = (const float*)d_in[17];

  float* ws = (float*)d_ws;
  float* stats = ws;
  int* cnts = (int*)ws;
  int* flags = (int*)(ws + FLAG_OFF);
  int* m1c = (int*)(ws + OFF_M1C);
  int* m2  = (int*)(ws + OFF_M2);
  int* m4  = (int*)(ws + OFF_M4);
  float* h1 = ws + OFF_H1;
  float* s2 = ws + OFF_S2;
  float* h3 = ws + OFF_H3;
  float* t3 = ws + OFF_T3;
  int* list1 = (int*)(ws + OFF_L1);
  int* list2 = (int*)(ws + OFF_L2);
  int* list4 = (int*)(ws + OFF_L4);
  int* bc1 = (int*)(ws + OFF_BC1);
  int* bc2 = (int*)(ws + OFF_BC2);
  int* bc4 = (int*)(ws + OFF_BC4);
  float* out = (float*)d_out;

  hipMemsetAsync(ws, 0, ST_ZERO * sizeof(float), stream);
  hipMemsetAsync(d_out, 0, (size_t)out_size * sizeof(float), stream);
  k_detect<<<256, 256, 0, stream>>>((const unsigned int*)mraw, flags);
  k_canon<<<NVOX1 / 256, 256, 0, stream>>>(mraw, m1c, flags, bc1);
  k_down1<<<NVOX2 / 256, 256, 0, stream>>>(m1c, m2, bc2);
  k_down2<<<NVOX4 / 256, 256, 0, stream>>>(m2, m4, bc4);
  k_scan<<<3, 1024, 0, stream>>>(bc1, bc2, bc4, cnts);
  k_scatter<<<2048 + 256 + 32, 256, 0, stream>>>(m1c, m2, m4, bc1, bc2, bc4, list1, list2, list4);
  k_conv1<<<1024, 256, 0, stream>>>(x, m1c, list1, cnts, w1, h1, stats);
  k_conv2<<<1024, 256, 0, stream>>>(h1, m1c, list2, cnts, w2, g1, b1, s2, stats);
  k_conv3<<<512, 512, 0, stream>>>(s2, m2, list4, cnts, w3, g2, b2, h3, stats);
  k_convt3<<<512, 512, 0, stream>>>(h3, m4, list2, cnts, w3t, g3, b3, t3, stats);
  k_convt2<<<512, 512, 0, stream>>>(t3, s2, m2, list1, cnts, w2t, g3t, b3t, g2, b2, out, stats);
  k_final<<<256, 256, 0, stream>>>(out, h1, list1, cnts, g2t, b2t, g1, b1, w1x1, stats);
}